// Round 5
// baseline (398.829 us; speedup 1.0000x reference)
//
#include <hip/hip_runtime.h>

#define EMBED_D 128
#define KNBR 50
#define MROWS 64      // padded neighbor rows for 16-row MFMA tiles
#define XSTR 264      // X row stride in bf16 elems (256 + 8 pad; row = 528 B, 16B-aligned)
#define NSTR 136      // nbr row stride in bf16 elems (128 + 8 pad)
#define ZROW 50       // index of the shared all-zero X row (for m=3 invalid lanes)

typedef __attribute__((ext_vector_type(8))) short short8;    // 8 bf16 = 4 VGPRs (MFMA A/B frag)
typedef __attribute__((ext_vector_type(4))) float floatx4;   // MFMA C/D frag

__device__ __forceinline__ float b2f(unsigned short u) {
    union { unsigned int i; float f; } v;
    v.i = ((unsigned int)u) << 16;
    return v.f;
}
__device__ __forceinline__ unsigned short f2b(float f) {
    union { float f; unsigned int i; } v;
    v.f = f;
    return (unsigned short)((v.i + 0x7fffu + ((v.i >> 16) & 1u)) >> 16);  // RNE, finite-only
}

// bf16 emb data (N(0,0.02)) decodes to |v| < 0.15 everywhere; fp32 data has
// random low-mantissa words -> some finite |v| >= 1.0 with P ~ 1-2e-10.
__device__ __forceinline__ bool detect_bf16(const unsigned short* p) {
    float mx = 0.f;
#pragma unroll
    for (int i = 0; i < 64; ++i) {
        const float a = fabsf(b2f(p[i]));
        if (a < 3.0e38f && a > mx) mx = a;
    }
    return mx < 1.0f;
}

// ---------------- fused preprocessing kernel ----------------

struct SmallTensors {
    const void* src[8];
    unsigned short* dst[8];
    int n[8];
};

__global__ void convert_all_kernel(const void* __restrict__ src, unsigned short* __restrict__ dst,
                                   long n8, SmallTensors st) {
    __shared__ int isbfS;
    if (threadIdx.x == 0) isbfS = detect_bf16((const unsigned short*)src) ? 1 : 0;
    __syncthreads();
    const bool isbf = (isbfS != 0);

    if (blockIdx.x == gridDim.x - 1) {     // last block: the small tensors
#pragma unroll
        for (int ti = 0; ti < 8; ++ti) {
            const int n = st.n[ti];
            for (int i = threadIdx.x; i < n; i += 256) {
                const float v = isbf ? b2f(((const unsigned short*)st.src[ti])[i])
                                     : ((const float*)st.src[ti])[i];
                st.dst[ti][i] = f2b(v);    // exact round-trip when already bf16
            }
        }
        return;
    }
    const long i = (long)blockIdx.x * 256 + threadIdx.x;
    if (i >= n8) return;
    if (isbf) {   // already bf16: straight 16B copy
        *(short8*)(dst + i * 8) = *(const short8*)((const unsigned short*)src + i * 8);
    } else {      // fp32 -> bf16 RNE
        const float* p = (const float*)src + i * 8;
        const floatx4 a = *(const floatx4*)p;
        const floatx4 c = *(const floatx4*)(p + 4);
        short8 r;
        r[0] = (short)f2b(a[0]); r[1] = (short)f2b(a[1]);
        r[2] = (short)f2b(a[2]); r[3] = (short)f2b(a[3]);
        r[4] = (short)f2b(c[0]); r[5] = (short)f2b(c[1]);
        r[6] = (short)f2b(c[2]); r[7] = (short)f2b(c[3]);
        *(short8*)(dst + i * 8) = r;
    }
}

// ---------------- main kernel (round-3 staged structure, union LDS, 5 blocks/CU) ----------------

__global__ __launch_bounds__(256, 5)
void embed_matcher_fast(const int* __restrict__ entity, const int* __restrict__ conn,
                        const unsigned short* __restrict__ emb,   // bf16 staged
                        const unsigned short* __restrict__ gw,
                        const unsigned short* __restrict__ gwb,
                        const unsigned short* __restrict__ gcnb,
                        const unsigned short* __restrict__ w1,
                        const unsigned short* __restrict__ b1,
                        const unsigned short* __restrict__ w2,
                        const unsigned short* __restrict__ b2,
                        const unsigned short* __restrict__ temp,
                        const void* __restrict__ emb_raw,         // for output-dtype probe
                        void* __restrict__ out)
{
    // Union buffer: phase 1 = X tile, 51 rows x XSTR (rows 0..49 data, row 50 zeros);
    // phase 2 (after barrier, X dead) = nbr tile, 64 rows x NSTR (8704 elems < 13464).
    __shared__ __align__(16) unsigned short XNs[(ZROW + 1) * XSTR];  // 26928 B
    __shared__ float selfE[EMBED_D];
    __shared__ float scoresS[MROWS];
    __shared__ float attnS[MROWS];
    __shared__ float gsumS[MROWS];
    __shared__ int flagS;

    const int t = threadIdx.x;
    const int b = blockIdx.x;
    const int lane = t & 63;
    const int wave = t >> 6;
    const int l15 = lane & 15;
    const int quad = lane >> 4;

    // ---- P0: weight fragments into registers (NT-GEMM layout, m92/m97-verified) ----
    short8 Bfrag[8][2];
#pragma unroll
    for (int ft = 0; ft < 8; ++ft)
#pragma unroll
        for (int nn = 0; nn < 2; ++nn) {
            const int dcol = wave * 32 + nn * 16 + l15;
            Bfrag[ft][nn] = *(const short8*)(gw + dcol * 256 + ft * 32 + quad * 8);
        }
    short8 W1frag[4];
#pragma unroll
    for (int ft = 0; ft < 4; ++ft)
        W1frag[ft] = *(const short8*)(w1 + (wave * 16 + l15) * 128 + ft * 32 + quad * 8);
    const float b1j = b2f(b1[wave * 16 + l15]);
    const float w2j = b2f(w2[wave * 16 + l15]);

    // ---- P0b: gather neighbor embeddings into LDS, zero row, self emb ----
    {
        const int cbase = b * (KNBR * 2);
        for (int c = t; c < KNBR * 2 * 16; c += 256) {   // 100 rows x 16 chunks of 8 elems
            const int r = c >> 4, j = c & 15;
            const int sym = conn[cbase + r];             // r = k*2 + half
            const short8 v = *(const short8*)(emb + (long)sym * EMBED_D + j * 8);
            *(short8*)(XNs + (r >> 1) * XSTR + (r & 1) * 128 + j * 8) = v;
        }
        const short8 z8 = {0, 0, 0, 0, 0, 0, 0, 0};
        if (t < 33)                                      // 528 B zero row, 33 chunks of 16B
            *(short8*)(XNs + ZROW * XSTR + t * 8) = z8;
        if (t < EMBED_D) selfE[t] = b2f(emb[(long)entity[b] * EMBED_D + t]);
        if (t < MROWS) gsumS[t] = b2f(b2[0]);            // gate logit accumulator init
        if (t == 0) flagS = detect_bf16((const unsigned short*)emb_raw) ? 1 : 0;
    }
    __syncthreads();

    // ---- P1: nbr = X(64x256) . W^T + gcn_w_b via mfma_f32_16x16x32_bf16 ----
    const int r3 = 48 + l15;
    const int row3 = (r3 < KNBR) ? r3 : ZROW;            // m=3 tail rows -> shared zero row

    floatx4 acc[4][2];
    const floatx4 fzero = {0.f, 0.f, 0.f, 0.f};
#pragma unroll
    for (int m = 0; m < 4; ++m)
#pragma unroll
        for (int nn = 0; nn < 2; ++nn) acc[m][nn] = fzero;
#pragma unroll
    for (int ft = 0; ft < 8; ++ft) {
        const int cofs = ft * 32 + quad * 8;
        short8 A[4];
#pragma unroll
        for (int m = 0; m < 3; ++m)
            A[m] = *(const short8*)(XNs + (m * 16 + l15) * XSTR + cofs);
        A[3] = *(const short8*)(XNs + row3 * XSTR + cofs);
#pragma unroll
        for (int m = 0; m < 4; ++m)
#pragma unroll
            for (int nn = 0; nn < 2; ++nn)
                acc[m][nn] = __builtin_amdgcn_mfma_f32_16x16x32_bf16(A[m], Bfrag[ft][nn], acc[m][nn], 0, 0, 0);
    }
    __syncthreads();   // X region dead; reuse XNs as the nbr tile

    // bias + store nbr to LDS (C/D layout: row = m*16 + quad*4 + r, col = dcol)
#pragma unroll
    for (int nn = 0; nn < 2; ++nn) {
        const int dcol = wave * 32 + nn * 16 + l15;
        const float bias = b2f(gwb[dcol]);
#pragma unroll
        for (int m = 0; m < 4; ++m)
#pragma unroll
            for (int r = 0; r < 4; ++r)
                XNs[(m * 16 + quad * 4 + r) * NSTR + dcol] = f2b(acc[m][nn][r] + bias);
    }
    __syncthreads();

    // ---- P2: scores[k] = (self . nbr[k]) / sqrt(128), 4 lanes per k ----
    {
        const int k = t >> 2, q = t & 3;
        float p = 0.f;
        if (k < KNBR) {
            const unsigned short* nr = XNs + k * NSTR + q * 32;
            const float* se = selfE + q * 32;
            short8 u0 = *(const short8*)(nr);
            short8 u1 = *(const short8*)(nr + 8);
            short8 u2 = *(const short8*)(nr + 16);
            short8 u3 = *(const short8*)(nr + 24);
#pragma unroll
            for (int i = 0; i < 8; ++i) {
                p += se[i]      * b2f((unsigned short)u0[i]);
                p += se[i + 8]  * b2f((unsigned short)u1[i]);
                p += se[i + 16] * b2f((unsigned short)u2[i]);
                p += se[i + 24] * b2f((unsigned short)u3[i]);
            }
        }
        p += __shfl_xor(p, 1);
        p += __shfl_xor(p, 2);
        if (k < KNBR && q == 0) scoresS[k] = p * 0.088388347648318447f;  // 1/sqrt(128)
    }
    __syncthreads();

    // ---- softmax over k (wave 0; other waves fall through to P3) ----
    if (t < 64) {
        const float s = (t < KNBR) ? scoresS[t] : -INFINITY;
        float mx = s;
#pragma unroll
        for (int o = 32; o > 0; o >>= 1) mx = fmaxf(mx, __shfl_xor(mx, o));
        const float e = (t < KNBR) ? expf(s - mx) : 0.f;
        float sum = e;
#pragma unroll
        for (int o = 32; o > 0; o >>= 1) sum += __shfl_xor(sum, o);
        attnS[t] = e / sum;
    }

    // ---- P3: gate MLP: h = relu(nbr.w1^T + b1); logit = h.w2 ----
    floatx4 acc2[4];
#pragma unroll
    for (int m = 0; m < 4; ++m) acc2[m] = fzero;
#pragma unroll
    for (int ft = 0; ft < 4; ++ft) {
        short8 A2[4];
#pragma unroll
        for (int m = 0; m < 4; ++m)
            A2[m] = *(const short8*)(XNs + (m * 16 + l15) * NSTR + ft * 32 + quad * 8);
#pragma unroll
        for (int m = 0; m < 4; ++m)
            acc2[m] = __builtin_amdgcn_mfma_f32_16x16x32_bf16(A2[m], W1frag[ft], acc2[m], 0, 0, 0);
    }
#pragma unroll
    for (int m = 0; m < 4; ++m)
#pragma unroll
        for (int r = 0; r < 4; ++r) {
            float c = fmaxf(acc2[m][r] + b1j, 0.f) * w2j;
            c += __shfl_xor(c, 1);   // sum the 16 h-cols held across l15
            c += __shfl_xor(c, 2);
            c += __shfl_xor(c, 4);
            c += __shfl_xor(c, 8);
            if (l15 == 0) atomicAdd(&gsumS[m * 16 + quad * 4 + r], c);
        }
    __syncthreads();

    // ---- P4a: fold gate into attn ----
    if (t < KNBR) {
        const float invT = 1.0f / b2f(temp[0]);
        const float g = 1.0f / (1.0f + expf(-gsumS[t] * invT));
        attnS[t] *= g;
    }
    __syncthreads();

    // ---- P4b: out[d] = tanh(max_k(attn*gate*nbr) + gcn_b) ----
    if (t < EMBED_D) {
        float mx = -INFINITY;
#pragma unroll
        for (int k = 0; k < KNBR; ++k)
            mx = fmaxf(mx, attnS[k] * b2f(XNs[k * NSTR + t]));
        const float o = tanhf(mx + b2f(gcnb[t]));
        if (flagS)
            ((unsigned short*)out)[(long)b * EMBED_D + t] = f2b(o);
        else
            ((float*)out)[(long)b * EMBED_D + t] = o;
    }
}

// ---------------- fallback (round-2 proven kernel, used only if ws too small) ----------------

template <bool BF16IN>
__device__ __forceinline__ short8 load8g(const void* base, long off) {
    if constexpr (BF16IN) {
        return *(const short8*)((const unsigned short*)base + off);
    } else {
        const float* p = (const float*)base + off;
        const floatx4 a = *(const floatx4*)p;
        const floatx4 c = *(const floatx4*)(p + 4);
        short8 r;
        r[0] = (short)f2b(a[0]); r[1] = (short)f2b(a[1]);
        r[2] = (short)f2b(a[2]); r[3] = (short)f2b(a[3]);
        r[4] = (short)f2b(c[0]); r[5] = (short)f2b(c[1]);
        r[6] = (short)f2b(c[2]); r[7] = (short)f2b(c[3]);
        return r;
    }
}
template <bool BF16IN>
__device__ __forceinline__ float loadSg(const void* base, long off) {
    if constexpr (BF16IN) return b2f(((const unsigned short*)base)[off]);
    else return ((const float*)base)[off];
}

template <bool BF16IN>
__device__ __forceinline__ void body_fb(
    const int* entity, const int* conn, const void* emb, const void* gw,
    const void* gwb, const void* gcnb, const void* w1, const void* b1,
    const void* w2, const void* b2, const void* temp, void* out,
    unsigned short* Xs, unsigned short* Ns,
    float* selfE, float* scoresS, float* attnS, float* gsumS)
{
    const int t = threadIdx.x, b = blockIdx.x;
    const int lane = t & 63, wave = t >> 6, l15 = lane & 15, quad = lane >> 4;
    short8 Bfrag[8][2];
#pragma unroll
    for (int ft = 0; ft < 8; ++ft)
#pragma unroll
        for (int nn = 0; nn < 2; ++nn)
            Bfrag[ft][nn] = load8g<BF16IN>(gw, (wave * 32 + nn * 16 + l15) * 256 + ft * 32 + quad * 8);
    short8 W1frag[4];
#pragma unroll
    for (int ft = 0; ft < 4; ++ft)
        W1frag[ft] = load8g<BF16IN>(w1, (wave * 16 + l15) * 128 + ft * 32 + quad * 8);
    const float b1j = loadSg<BF16IN>(b1, wave * 16 + l15);
    const float w2j = loadSg<BF16IN>(w2, wave * 16 + l15);
    {
        const int cbase = b * (KNBR * 2);
        for (int c = t; c < KNBR * 2 * 16; c += 256) {
            const int r = c >> 4, j = c & 15;
            const int sym = conn[cbase + r];
            *(short8*)(Xs + (r >> 1) * XSTR + (r & 1) * 128 + j * 8) =
                load8g<BF16IN>(emb, (long)sym * EMBED_D + j * 8);
        }
        for (int i = t; i < (MROWS - KNBR) * 256; i += 256)
            Xs[(KNBR + (i >> 8)) * XSTR + (i & 255)] = 0;
        if (t < EMBED_D) selfE[t] = loadSg<BF16IN>(emb, (long)entity[b] * EMBED_D + t);
        if (t < MROWS) gsumS[t] = loadSg<BF16IN>(b2, 0);
    }
    __syncthreads();
    floatx4 acc[4][2];
    const floatx4 fzero = {0.f, 0.f, 0.f, 0.f};
#pragma unroll
    for (int m = 0; m < 4; ++m)
#pragma unroll
        for (int nn = 0; nn < 2; ++nn) acc[m][nn] = fzero;
#pragma unroll
    for (int ft = 0; ft < 8; ++ft) {
        short8 A[4];
#pragma unroll
        for (int m = 0; m < 4; ++m)
            A[m] = *(const short8*)(Xs + (m * 16 + l15) * XSTR + ft * 32 + quad * 8);
#pragma unroll
        for (int m = 0; m < 4; ++m)
#pragma unroll
            for (int nn = 0; nn < 2; ++nn)
                acc[m][nn] = __builtin_amdgcn_mfma_f32_16x16x32_bf16(A[m], Bfrag[ft][nn], acc[m][nn], 0, 0, 0);
    }
#pragma unroll
    for (int nn = 0; nn < 2; ++nn) {
        const int dcol = wave * 32 + nn * 16 + l15;
        const float bias = loadSg<BF16IN>(gwb, dcol);
#pragma unroll
        for (int m = 0; m < 4; ++m)
#pragma unroll
            for (int r = 0; r < 4; ++r)
                Ns[(m * 16 + quad * 4 + r) * NSTR + dcol] = f2b(acc[m][nn][r] + bias);
    }
    __syncthreads();
    {
        const int k = t >> 2, q = t & 3;
        float p = 0.f;
        if (k < KNBR) {
            const unsigned short* nr = Ns + k * NSTR + q * 32;
            const float* se = selfE + q * 32;
#pragma unroll
            for (int i = 0; i < 32; ++i) p += se[i] * b2f(nr[i]);
        }
        p += __shfl_xor(p, 1);
        p += __shfl_xor(p, 2);
        if (k < KNBR && q == 0) scoresS[k] = p * 0.088388347648318447f;
    }
    __syncthreads();
    if (t < 64) {
        const float s = (t < KNBR) ? scoresS[t] : -INFINITY;
        float mx = s;
#pragma unroll
        for (int o = 32; o > 0; o >>= 1) mx = fmaxf(mx, __shfl_xor(mx, o));
        const float e = (t < KNBR) ? expf(s - mx) : 0.f;
        float sum = e;
#pragma unroll
        for (int o = 32; o > 0; o >>= 1) sum += __shfl_xor(sum, o);
        attnS[t] = e / sum;
    }
    floatx4 acc2[4];
#pragma unroll
    for (int m = 0; m < 4; ++m) acc2[m] = fzero;
#pragma unroll
    for (int ft = 0; ft < 4; ++ft) {
        short8 A2[4];
#pragma unroll
        for (int m = 0; m < 4; ++m)
            A2[m] = *(const short8*)(Ns + (m * 16 + l15) * NSTR + ft * 32 + quad * 8);
#pragma unroll
        for (int m = 0; m < 4; ++m)
            acc2[m] = __builtin_amdgcn_mfma_f32_16x16x32_bf16(A2[m], W1frag[ft], acc2[m], 0, 0, 0);
    }
#pragma unroll
    for (int m = 0; m < 4; ++m)
#pragma unroll
        for (int r = 0; r < 4; ++r) {
            float c = fmaxf(acc2[m][r] + b1j, 0.f) * w2j;
            c += __shfl_xor(c, 1); c += __shfl_xor(c, 2);
            c += __shfl_xor(c, 4); c += __shfl_xor(c, 8);
            if (l15 == 0) atomicAdd(&gsumS[m * 16 + quad * 4 + r], c);
        }
    __syncthreads();
    if (t < KNBR) {
        const float invT = 1.0f / loadSg<BF16IN>(temp, 0);
        attnS[t] *= 1.0f / (1.0f + expf(-gsumS[t] * invT));
    }
    __syncthreads();
    if (t < EMBED_D) {
        float mx = -INFINITY;
        for (int k = 0; k < KNBR; ++k)
            mx = fmaxf(mx, attnS[k] * b2f(Ns[k * NSTR + t]));
        const float o = tanhf(mx + loadSg<BF16IN>(gcnb, t));
        if constexpr (BF16IN)
            ((unsigned short*)out)[(long)b * EMBED_D + t] = f2b(o);
        else
            ((float*)out)[(long)b * EMBED_D + t] = o;
    }
}

__global__ __launch_bounds__(256, 2)
void embed_matcher_fallback(const int* entity, const int* conn, const void* emb,
                            const void* gw, const void* gwb, const void* gcnb,
                            const void* w1, const void* b1, const void* w2,
                            const void* b2, const void* temp, void* out)
{
    __shared__ __align__(16) unsigned short Xs[MROWS * XSTR];
    __shared__ __align__(16) unsigned short Ns[MROWS * NSTR];
    __shared__ float selfE[EMBED_D];
    __shared__ float scoresS[MROWS];
    __shared__ float attnS[MROWS];
    __shared__ float gsumS[MROWS];
    if (detect_bf16((const unsigned short*)emb))
        body_fb<true>(entity, conn, emb, gw, gwb, gcnb, w1, b1, w2, b2, temp, out,
                      Xs, Ns, selfE, scoresS, attnS, gsumS);
    else
        body_fb<false>(entity, conn, emb, gw, gwb, gcnb, w1, b1, w2, b2, temp, out,
                       Xs, Ns, selfE, scoresS, attnS, gsumS);
}

// ---------------- launcher ----------------

static inline size_t align256(size_t x) { return (x + 255) & ~(size_t)255; }

extern "C" void kernel_launch(void* const* d_in, const int* in_sizes, int n_in,
                              void* d_out, int out_size, void* d_ws, size_t ws_size,
                              hipStream_t stream) {
    (void)n_in; (void)out_size;
    const int B = in_sizes[0];  // 8192

    // ws layout: bf16 copies of all float tensors
    const long n_emb = in_sizes[2];
    size_t off[9], cur = 0;
    const int ns[8] = {in_sizes[3], in_sizes[4], in_sizes[5], in_sizes[6],
                       in_sizes[7], in_sizes[8], in_sizes[9], in_sizes[10]};
    off[0] = 0; cur = align256((size_t)n_emb * 2);                      // emb
    for (int i = 0; i < 8; ++i) { off[i + 1] = cur; cur = align256(cur + (size_t)ns[i] * 2); }

    if (ws_size < cur) {
        embed_matcher_fallback<<<B, 256, 0, stream>>>(
            (const int*)d_in[0], (const int*)d_in[1],
            d_in[2], d_in[3], d_in[4], d_in[5],
            d_in[6], d_in[7], d_in[8], d_in[9], d_in[10], d_out);
        return;
    }

    char* ws = (char*)d_ws;
    unsigned short* emb_b = (unsigned short*)(ws + off[0]);

    SmallTensors st;
    for (int i = 0; i < 8; ++i) {
        st.src[i] = d_in[3 + i];
        st.dst[i] = (unsigned short*)(ws + off[i + 1]);
        st.n[i] = ns[i];
    }

    const long n8 = n_emb / 8;   // 12,800,128 / 8
    const int nblk = (int)((n8 + 255) / 256) + 1;   // +1: last block converts small tensors
    convert_all_kernel<<<nblk, 256, 0, stream>>>(d_in[2], emb_b, n8, st);

    embed_matcher_fast<<<B, 256, 0, stream>>>(
        (const int*)d_in[0], (const int*)d_in[1],
        emb_b,
        (const unsigned short*)(ws + off[1]),   // gw
        (const unsigned short*)(ws + off[2]),   // gwb
        (const unsigned short*)(ws + off[3]),   // gcnb
        (const unsigned short*)(ws + off[4]),   // w1
        (const unsigned short*)(ws + off[5]),   // b1
        (const unsigned short*)(ws + off[6]),   // w2
        (const unsigned short*)(ws + off[7]),   // b2
        (const unsigned short*)(ws + off[8]),   // temp
        d_in[2],                                // raw emb for dtype probe
        d_out);
}

// Round 6
// 331.687 us; speedup vs baseline: 1.2024x; 1.2024x over previous
//
#include <hip/hip_runtime.h>

#define EMBED_D 128
#define KNBR 50
#define MROWS 64      // padded neighbor rows for 16-row MFMA tiles
#define XSTR 264      // X row stride in bf16 elems (256 + 8 pad; row = 528 B, 16B-aligned)
#define NSTR 136      // nbr row stride in bf16 elems (128 + 8 pad)
#define ZROW 50       // index of the shared all-zero X row (for m=3 invalid lanes)

typedef __attribute__((ext_vector_type(8))) short short8;    // 8 bf16 = 4 VGPRs (MFMA A/B frag)
typedef __attribute__((ext_vector_type(4))) float floatx4;   // MFMA C/D frag

__device__ __forceinline__ float b2f(unsigned short u) {
    union { unsigned int i; float f; } v;
    v.i = ((unsigned int)u) << 16;
    return v.f;
}
__device__ __forceinline__ unsigned short f2b(float f) {
    union { float f; unsigned int i; } v;
    v.f = f;
    return (unsigned short)((v.i + 0x7fffu + ((v.i >> 16) & 1u)) >> 16);  // RNE, finite-only
}

// bf16 emb data (N(0,0.02)) decodes to |v| < 0.15 everywhere; fp32 data has
// random low-mantissa words -> some finite |v| >= 1.0 with P ~ 1-2e-10.
__device__ __forceinline__ bool detect_bf16(const unsigned short* p) {
    float mx = 0.f;
#pragma unroll
    for (int i = 0; i < 64; ++i) {
        const float a = fabsf(b2f(p[i]));
        if (a < 3.0e38f && a > mx) mx = a;
    }
    return mx < 1.0f;
}

// ---------------- fused preprocessing kernel ----------------

struct SmallTensors {
    const void* src[8];
    unsigned short* dst[8];
    int n[8];
};

__global__ void convert_all_kernel(const void* __restrict__ src, unsigned short* __restrict__ dst,
                                   long n8, SmallTensors st) {
    __shared__ int isbfS;
    if (threadIdx.x == 0) isbfS = detect_bf16((const unsigned short*)src) ? 1 : 0;
    __syncthreads();
    const bool isbf = (isbfS != 0);

    if (blockIdx.x == gridDim.x - 1) {     // last block: the small tensors
#pragma unroll
        for (int ti = 0; ti < 8; ++ti) {
            const int n = st.n[ti];
            for (int i = threadIdx.x; i < n; i += 256) {
                const float v = isbf ? b2f(((const unsigned short*)st.src[ti])[i])
                                     : ((const float*)st.src[ti])[i];
                st.dst[ti][i] = f2b(v);    // exact round-trip when already bf16
            }
        }
        return;
    }
    const long i = (long)blockIdx.x * 256 + threadIdx.x;
    if (i >= n8) return;
    if (isbf) {   // already bf16: straight 16B copy
        *(short8*)(dst + i * 8) = *(const short8*)((const unsigned short*)src + i * 8);
    } else {      // fp32 -> bf16 RNE
        const float* p = (const float*)src + i * 8;
        const floatx4 a = *(const floatx4*)p;
        const floatx4 c = *(const floatx4*)(p + 4);
        short8 r;
        r[0] = (short)f2b(a[0]); r[1] = (short)f2b(a[1]);
        r[2] = (short)f2b(a[2]); r[3] = (short)f2b(a[3]);
        r[4] = (short)f2b(c[0]); r[5] = (short)f2b(c[1]);
        r[6] = (short)f2b(c[2]); r[7] = (short)f2b(c[3]);
        *(short8*)(dst + i * 8) = r;
    }
}

// ---------------- main kernel ----------------
// __launch_bounds__(256, 4): min 4 waves/EU -> VGPR cap 128. (256,5) forces the
// <=64-VGPR wave bucket (m69 granularity) -> massive scratch spills (r4/r5:
// WRITE_SIZE 87/290 MB vs 4 MB clean). 4 blocks/CU, LDS 28.7 KB not binding.

__global__ __launch_bounds__(256, 4)
void embed_matcher_fast(const int* __restrict__ entity, const int* __restrict__ conn,
                        const unsigned short* __restrict__ emb,   // bf16 staged
                        const unsigned short* __restrict__ gw,
                        const unsigned short* __restrict__ gwb,
                        const unsigned short* __restrict__ gcnb,
                        const unsigned short* __restrict__ w1,
                        const unsigned short* __restrict__ b1,
                        const unsigned short* __restrict__ w2,
                        const unsigned short* __restrict__ b2,
                        const unsigned short* __restrict__ temp,
                        const void* __restrict__ emb_raw,         // for output-dtype probe
                        void* __restrict__ out)
{
    // Union buffer: phase 1 = X tile, 51 rows x XSTR (rows 0..49 data, row 50 zeros);
    // phase 2 (after barrier, X dead) = nbr tile, 64 rows x NSTR (8704 elems < 13464).
    __shared__ __align__(16) unsigned short XNs[(ZROW + 1) * XSTR];  // 26928 B
    __shared__ float selfE[EMBED_D];
    __shared__ float scoresS[MROWS];
    __shared__ float attnS[MROWS];
    __shared__ float gsumS[MROWS];
    __shared__ int flagS;

    const int t = threadIdx.x;
    const int b = blockIdx.x;
    const int lane = t & 63;
    const int wave = t >> 6;
    const int l15 = lane & 15;
    const int quad = lane >> 4;

    // ---- P0: weight fragments into registers (NT-GEMM layout, m92/m97-verified) ----
    short8 Bfrag[8][2];
#pragma unroll
    for (int ft = 0; ft < 8; ++ft)
#pragma unroll
        for (int nn = 0; nn < 2; ++nn) {
            const int dcol = wave * 32 + nn * 16 + l15;
            Bfrag[ft][nn] = *(const short8*)(gw + dcol * 256 + ft * 32 + quad * 8);
        }
    short8 W1frag[4];
#pragma unroll
    for (int ft = 0; ft < 4; ++ft)
        W1frag[ft] = *(const short8*)(w1 + (wave * 16 + l15) * 128 + ft * 32 + quad * 8);
    const float b1j = b2f(b1[wave * 16 + l15]);
    const float w2j = b2f(w2[wave * 16 + l15]);

    // ---- P0b: gather neighbor embeddings into LDS, zero row, self emb ----
    {
        const int cbase = b * (KNBR * 2);
        for (int c = t; c < KNBR * 2 * 16; c += 256) {   // 100 rows x 16 chunks of 8 elems
            const int r = c >> 4, j = c & 15;
            const int sym = conn[cbase + r];             // r = k*2 + half
            const short8 v = *(const short8*)(emb + (long)sym * EMBED_D + j * 8);
            *(short8*)(XNs + (r >> 1) * XSTR + (r & 1) * 128 + j * 8) = v;
        }
        const short8 z8 = {0, 0, 0, 0, 0, 0, 0, 0};
        if (t < 33)                                      // 528 B zero row, 33 chunks of 16B
            *(short8*)(XNs + ZROW * XSTR + t * 8) = z8;
        if (t < EMBED_D) selfE[t] = b2f(emb[(long)entity[b] * EMBED_D + t]);
        if (t < MROWS) gsumS[t] = b2f(b2[0]);            // gate logit accumulator init
        if (t == 0) flagS = detect_bf16((const unsigned short*)emb_raw) ? 1 : 0;
    }
    __syncthreads();

    // ---- P1: nbr = X(64x256) . W^T + gcn_w_b via mfma_f32_16x16x32_bf16 ----
    const int r3 = 48 + l15;
    const int row3 = (r3 < KNBR) ? r3 : ZROW;            // m=3 tail rows -> shared zero row

    floatx4 acc[4][2];
    const floatx4 fzero = {0.f, 0.f, 0.f, 0.f};
#pragma unroll
    for (int m = 0; m < 4; ++m)
#pragma unroll
        for (int nn = 0; nn < 2; ++nn) acc[m][nn] = fzero;
#pragma unroll
    for (int ft = 0; ft < 8; ++ft) {
        const int cofs = ft * 32 + quad * 8;
        short8 A[4];
#pragma unroll
        for (int m = 0; m < 3; ++m)
            A[m] = *(const short8*)(XNs + (m * 16 + l15) * XSTR + cofs);
        A[3] = *(const short8*)(XNs + row3 * XSTR + cofs);
#pragma unroll
        for (int m = 0; m < 4; ++m)
#pragma unroll
            for (int nn = 0; nn < 2; ++nn)
                acc[m][nn] = __builtin_amdgcn_mfma_f32_16x16x32_bf16(A[m], Bfrag[ft][nn], acc[m][nn], 0, 0, 0);
    }
    __syncthreads();   // X region dead; reuse XNs as the nbr tile

    // bias + store nbr to LDS (C/D layout: row = m*16 + quad*4 + r, col = dcol)
#pragma unroll
    for (int nn = 0; nn < 2; ++nn) {
        const int dcol = wave * 32 + nn * 16 + l15;
        const float bias = b2f(gwb[dcol]);
#pragma unroll
        for (int m = 0; m < 4; ++m)
#pragma unroll
            for (int r = 0; r < 4; ++r)
                XNs[(m * 16 + quad * 4 + r) * NSTR + dcol] = f2b(acc[m][nn][r] + bias);
    }
    __syncthreads();

    // ---- P2: scores[k] = (self . nbr[k]) / sqrt(128), 4 lanes per k ----
    {
        const int k = t >> 2, q = t & 3;
        float p = 0.f;
        if (k < KNBR) {
            const unsigned short* nr = XNs + k * NSTR + q * 32;
            const float* se = selfE + q * 32;
            short8 u0 = *(const short8*)(nr);
            short8 u1 = *(const short8*)(nr + 8);
            short8 u2 = *(const short8*)(nr + 16);
            short8 u3 = *(const short8*)(nr + 24);
#pragma unroll
            for (int i = 0; i < 8; ++i) {
                p += se[i]      * b2f((unsigned short)u0[i]);
                p += se[i + 8]  * b2f((unsigned short)u1[i]);
                p += se[i + 16] * b2f((unsigned short)u2[i]);
                p += se[i + 24] * b2f((unsigned short)u3[i]);
            }
        }
        p += __shfl_xor(p, 1);
        p += __shfl_xor(p, 2);
        if (k < KNBR && q == 0) scoresS[k] = p * 0.088388347648318447f;  // 1/sqrt(128)
    }
    __syncthreads();

    // ---- softmax over k (wave 0; other waves fall through to P3) ----
    if (t < 64) {
        const float s = (t < KNBR) ? scoresS[t] : -INFINITY;
        float mx = s;
#pragma unroll
        for (int o = 32; o > 0; o >>= 1) mx = fmaxf(mx, __shfl_xor(mx, o));
        const float e = (t < KNBR) ? expf(s - mx) : 0.f;
        float sum = e;
#pragma unroll
        for (int o = 32; o > 0; o >>= 1) sum += __shfl_xor(sum, o);
        attnS[t] = e / sum;
    }

    // ---- P3: gate MLP: h = relu(nbr.w1^T + b1); logit = h.w2 ----
    floatx4 acc2[4];
#pragma unroll
    for (int m = 0; m < 4; ++m) acc2[m] = fzero;
#pragma unroll
    for (int ft = 0; ft < 4; ++ft) {
        short8 A2[4];
#pragma unroll
        for (int m = 0; m < 4; ++m)
            A2[m] = *(const short8*)(XNs + (m * 16 + l15) * NSTR + ft * 32 + quad * 8);
#pragma unroll
        for (int m = 0; m < 4; ++m)
            acc2[m] = __builtin_amdgcn_mfma_f32_16x16x32_bf16(A2[m], W1frag[ft], acc2[m], 0, 0, 0);
    }
#pragma unroll
    for (int m = 0; m < 4; ++m)
#pragma unroll
        for (int r = 0; r < 4; ++r) {
            float c = fmaxf(acc2[m][r] + b1j, 0.f) * w2j;
            c += __shfl_xor(c, 1);   // sum the 16 h-cols held across l15
            c += __shfl_xor(c, 2);
            c += __shfl_xor(c, 4);
            c += __shfl_xor(c, 8);
            if (l15 == 0) atomicAdd(&gsumS[m * 16 + quad * 4 + r], c);
        }
    __syncthreads();

    // ---- P4a: fold gate into attn ----
    if (t < KNBR) {
        const float invT = 1.0f / b2f(temp[0]);
        const float g = 1.0f / (1.0f + expf(-gsumS[t] * invT));
        attnS[t] *= g;
    }
    __syncthreads();

    // ---- P4b: out[d] = tanh(max_k(attn*gate*nbr) + gcn_b) ----
    if (t < EMBED_D) {
        float mx = -INFINITY;
#pragma unroll
        for (int k = 0; k < KNBR; ++k)
            mx = fmaxf(mx, attnS[k] * b2f(XNs[k * NSTR + t]));
        const float o = tanhf(mx + b2f(gcnb[t]));
        if (flagS)
            ((unsigned short*)out)[(long)b * EMBED_D + t] = f2b(o);
        else
            ((float*)out)[(long)b * EMBED_D + t] = o;
    }
}

// ---------------- fallback (round-2 proven kernel, used only if ws too small) ----------------

template <bool BF16IN>
__device__ __forceinline__ short8 load8g(const void* base, long off) {
    if constexpr (BF16IN) {
        return *(const short8*)((const unsigned short*)base + off);
    } else {
        const float* p = (const float*)base + off;
        const floatx4 a = *(const floatx4*)p;
        const floatx4 c = *(const floatx4*)(p + 4);
        short8 r;
        r[0] = (short)f2b(a[0]); r[1] = (short)f2b(a[1]);
        r[2] = (short)f2b(a[2]); r[3] = (short)f2b(a[3]);
        r[4] = (short)f2b(c[0]); r[5] = (short)f2b(c[1]);
        r[6] = (short)f2b(c[2]); r[7] = (short)f2b(c[3]);
        return r;
    }
}
template <bool BF16IN>
__device__ __forceinline__ float loadSg(const void* base, long off) {
    if constexpr (BF16IN) return b2f(((const unsigned short*)base)[off]);
    else return ((const float*)base)[off];
}

template <bool BF16IN>
__device__ __forceinline__ void body_fb(
    const int* entity, const int* conn, const void* emb, const void* gw,
    const void* gwb, const void* gcnb, const void* w1, const void* b1,
    const void* w2, const void* b2, const void* temp, void* out,
    unsigned short* Xs, unsigned short* Ns,
    float* selfE, float* scoresS, float* attnS, float* gsumS)
{
    const int t = threadIdx.x, b = blockIdx.x;
    const int lane = t & 63, wave = t >> 6, l15 = lane & 15, quad = lane >> 4;
    short8 Bfrag[8][2];
#pragma unroll
    for (int ft = 0; ft < 8; ++ft)
#pragma unroll
        for (int nn = 0; nn < 2; ++nn)
            Bfrag[ft][nn] = load8g<BF16IN>(gw, (wave * 32 + nn * 16 + l15) * 256 + ft * 32 + quad * 8);
    short8 W1frag[4];
#pragma unroll
    for (int ft = 0; ft < 4; ++ft)
        W1frag[ft] = load8g<BF16IN>(w1, (wave * 16 + l15) * 128 + ft * 32 + quad * 8);
    const float b1j = loadSg<BF16IN>(b1, wave * 16 + l15);
    const float w2j = loadSg<BF16IN>(w2, wave * 16 + l15);
    {
        const int cbase = b * (KNBR * 2);
        for (int c = t; c < KNBR * 2 * 16; c += 256) {
            const int r = c >> 4, j = c & 15;
            const int sym = conn[cbase + r];
            *(short8*)(Xs + (r >> 1) * XSTR + (r & 1) * 128 + j * 8) =
                load8g<BF16IN>(emb, (long)sym * EMBED_D + j * 8);
        }
        for (int i = t; i < (MROWS - KNBR) * 256; i += 256)
            Xs[(KNBR + (i >> 8)) * XSTR + (i & 255)] = 0;
        if (t < EMBED_D) selfE[t] = loadSg<BF16IN>(emb, (long)entity[b] * EMBED_D + t);
        if (t < MROWS) gsumS[t] = loadSg<BF16IN>(b2, 0);
    }
    __syncthreads();
    floatx4 acc[4][2];
    const floatx4 fzero = {0.f, 0.f, 0.f, 0.f};
#pragma unroll
    for (int m = 0; m < 4; ++m)
#pragma unroll
        for (int nn = 0; nn < 2; ++nn) acc[m][nn] = fzero;
#pragma unroll
    for (int ft = 0; ft < 8; ++ft) {
        short8 A[4];
#pragma unroll
        for (int m = 0; m < 4; ++m)
            A[m] = *(const short8*)(Xs + (m * 16 + l15) * XSTR + ft * 32 + quad * 8);
#pragma unroll
        for (int m = 0; m < 4; ++m)
#pragma unroll
            for (int nn = 0; nn < 2; ++nn)
                acc[m][nn] = __builtin_amdgcn_mfma_f32_16x16x32_bf16(A[m], Bfrag[ft][nn], acc[m][nn], 0, 0, 0);
    }
#pragma unroll
    for (int nn = 0; nn < 2; ++nn) {
        const int dcol = wave * 32 + nn * 16 + l15;
        const float bias = loadSg<BF16IN>(gwb, dcol);
#pragma unroll
        for (int m = 0; m < 4; ++m)
#pragma unroll
            for (int r = 0; r < 4; ++r)
                Ns[(m * 16 + quad * 4 + r) * NSTR + dcol] = f2b(acc[m][nn][r] + bias);
    }
    __syncthreads();
    {
        const int k = t >> 2, q = t & 3;
        float p = 0.f;
        if (k < KNBR) {
            const unsigned short* nr = Ns + k * NSTR + q * 32;
            const float* se = selfE + q * 32;
#pragma unroll
            for (int i = 0; i < 32; ++i) p += se[i] * b2f(nr[i]);
        }
        p += __shfl_xor(p, 1);
        p += __shfl_xor(p, 2);
        if (k < KNBR && q == 0) scoresS[k] = p * 0.088388347648318447f;
    }
    __syncthreads();
    if (t < 64) {
        const float s = (t < KNBR) ? scoresS[t] : -INFINITY;
        float mx = s;
#pragma unroll
        for (int o = 32; o > 0; o >>= 1) mx = fmaxf(mx, __shfl_xor(mx, o));
        const float e = (t < KNBR) ? expf(s - mx) : 0.f;
        float sum = e;
#pragma unroll
        for (int o = 32; o > 0; o >>= 1) sum += __shfl_xor(sum, o);
        attnS[t] = e / sum;
    }
    floatx4 acc2[4];
#pragma unroll
    for (int m = 0; m < 4; ++m) acc2[m] = fzero;
#pragma unroll
    for (int ft = 0; ft < 4; ++ft) {
        short8 A2[4];
#pragma unroll
        for (int m = 0; m < 4; ++m)
            A2[m] = *(const short8*)(Ns + (m * 16 + l15) * NSTR + ft * 32 + quad * 8);
#pragma unroll
        for (int m = 0; m < 4; ++m)
            acc2[m] = __builtin_amdgcn_mfma_f32_16x16x32_bf16(A2[m], W1frag[ft], acc2[m], 0, 0, 0);
    }
#pragma unroll
    for (int m = 0; m < 4; ++m)
#pragma unroll
        for (int r = 0; r < 4; ++r) {
            float c = fmaxf(acc2[m][r] + b1j, 0.f) * w2j;
            c += __shfl_xor(c, 1); c += __shfl_xor(c, 2);
            c += __shfl_xor(c, 4); c += __shfl_xor(c, 8);
            if (l15 == 0) atomicAdd(&gsumS[m * 16 + quad * 4 + r], c);
        }
    __syncthreads();
    if (t < KNBR) {
        const float invT = 1.0f / loadSg<BF16IN>(temp, 0);
        attnS[t] *= 1.0f / (1.0f + expf(-gsumS[t] * invT));
    }
    __syncthreads();
    if (t < EMBED_D) {
        float mx = -INFINITY;
        for (int k = 0; k < KNBR; ++k)
            mx = fmaxf(mx, attnS[k] * b2f(Ns[k * NSTR + t]));
        const float o = tanhf(mx + loadSg<BF16IN>(gcnb, t));
        if constexpr (BF16IN)
            ((unsigned short*)out)[(long)b * EMBED_D + t] = f2b(o);
        else
            ((float*)out)[(long)b * EMBED_D + t] = o;
    }
}

__global__ __launch_bounds__(256, 2)
void embed_matcher_fallback(const int* entity, const int* conn, const void* emb,
                            const void* gw, const void* gwb, const void* gcnb,
                            const void* w1, const void* b1, const void* w2,
                            const void* b2, const void* temp, void* out)
{
    __shared__ __align__(16) unsigned short Xs[MROWS * XSTR];
    __shared__ __align__(16) unsigned short Ns[MROWS * NSTR];
    __shared__ float selfE[EMBED_D];
    __shared__ float scoresS[MROWS];
    __shared__ float attnS[MROWS];
    __shared__ float gsumS[MROWS];
    if (detect_bf16((const unsigned short*)emb))
        body_fb<true>(entity, conn, emb, gw, gwb, gcnb, w1, b1, w2, b2, temp, out,
                      Xs, Ns, selfE, scoresS, attnS, gsumS);
    else
        body_fb<false>(entity, conn, emb, gw, gwb, gcnb, w1, b1, w2, b2, temp, out,
                       Xs, Ns, selfE, scoresS, attnS, gsumS);
}

// ---------------- launcher ----------------

static inline size_t align256(size_t x) { return (x + 255) & ~(size_t)255; }

extern "C" void kernel_launch(void* const* d_in, const int* in_sizes, int n_in,
                              void* d_out, int out_size, void* d_ws, size_t ws_size,
                              hipStream_t stream) {
    (void)n_in; (void)out_size;
    const int B = in_sizes[0];  // 8192

    // ws layout: bf16 copies of all float tensors
    const long n_emb = in_sizes[2];
    size_t off[9], cur = 0;
    const int ns[8] = {in_sizes[3], in_sizes[4], in_sizes[5], in_sizes[6],
                       in_sizes[7], in_sizes[8], in_sizes[9], in_sizes[10]};
    off[0] = 0; cur = align256((size_t)n_emb * 2);                      // emb
    for (int i = 0; i < 8; ++i) { off[i + 1] = cur; cur = align256(cur + (size_t)ns[i] * 2); }

    if (ws_size < cur) {
        embed_matcher_fallback<<<B, 256, 0, stream>>>(
            (const int*)d_in[0], (const int*)d_in[1],
            d_in[2], d_in[3], d_in[4], d_in[5],
            d_in[6], d_in[7], d_in[8], d_in[9], d_in[10], d_out);
        return;
    }

    char* ws = (char*)d_ws;
    unsigned short* emb_b = (unsigned short*)(ws + off[0]);

    SmallTensors st;
    for (int i = 0; i < 8; ++i) {
        st.src[i] = d_in[3 + i];
        st.dst[i] = (unsigned short*)(ws + off[i + 1]);
        st.n[i] = ns[i];
    }

    const long n8 = n_emb / 8;   // 12,800,128 / 8
    const int nblk = (int)((n8 + 255) / 256) + 1;   // +1: last block converts small tensors
    convert_all_kernel<<<nblk, 256, 0, stream>>>(d_in[2], emb_b, n8, st);

    embed_matcher_fast<<<B, 256, 0, stream>>>(
        (const int*)d_in[0], (const int*)d_in[1],
        emb_b,
        (const unsigned short*)(ws + off[1]),   // gw
        (const unsigned short*)(ws + off[2]),   // gwb
        (const unsigned short*)(ws + off[3]),   // gcnb
        (const unsigned short*)(ws + off[4]),   // w1
        (const unsigned short*)(ws + off[5]),   // b1
        (const unsigned short*)(ws + off[6]),   // w2
        (const unsigned short*)(ws + off[7]),   // b2
        (const unsigned short*)(ws + off[8]),   // temp
        d_in[2],                                // raw emb for dtype probe
        d_out);
}

// Round 7
// 284.954 us; speedup vs baseline: 1.3996x; 1.1640x over previous
//
#include <hip/hip_runtime.h>

#define EMBED_D 128
#define KNBR 50
#define MROWS 64      // padded neighbor rows for 16-row MFMA tiles
#define XSTR 264      // X row stride in bf16 elems (256 + 8 pad; row = 528 B, 16B-aligned)
#define NSTR 136      // nbr row stride in bf16 elems (128 + 8 pad)
#define ZROW 50       // index of the shared all-zero X row (for m=3 invalid lanes)

typedef __attribute__((ext_vector_type(8))) short short8;    // 8 bf16 = 4 VGPRs (MFMA A/B frag)
typedef __attribute__((ext_vector_type(4))) float floatx4;   // MFMA C/D frag

__device__ __forceinline__ float b2f(unsigned short u) {
    union { unsigned int i; float f; } v;
    v.i = ((unsigned int)u) << 16;
    return v.f;
}
__device__ __forceinline__ unsigned short f2b(float f) {
    union { float f; unsigned int i; } v;
    v.f = f;
    return (unsigned short)((v.i + 0x7fffu + ((v.i >> 16) & 1u)) >> 16);  // RNE, finite-only
}

// bf16 emb data (N(0,0.02)) decodes to |v| < 0.15 everywhere; fp32 data has
// random low-mantissa words -> some finite |v| >= 1.0 with P ~ 1-2e-10.
__device__ __forceinline__ bool detect_bf16(const unsigned short* p) {
    float mx = 0.f;
#pragma unroll
    for (int i = 0; i < 64; ++i) {
        const float a = fabsf(b2f(p[i]));
        if (a < 3.0e38f && a > mx) mx = a;
    }
    return mx < 1.0f;
}

// ---------------- preprocessing: one launch, no straggler block ----------------
// Grid = nEmb blocks (emb chunks) + 20 blocks (gw+w1, exactly 1 chunk/thread)
// + 1 block (6 tiny tensors). r6's fused version made ONE block convert gw in a
// 128-iteration rolled loop -> ~40 us straggler (kernel time = max block).

struct TinyTensors {
    const void* src[6];
    unsigned short* dst[6];
    int n[6];
};

__device__ __forceinline__ void conv_chunk(const void* src, unsigned short* dst,
                                           long i, bool isbf) {
    if (isbf) {
        *(short8*)(dst + i * 8) = *(const short8*)((const unsigned short*)src + i * 8);
    } else {
        const float* p = (const float*)src + i * 8;
        const floatx4 a = *(const floatx4*)p;
        const floatx4 c = *(const floatx4*)(p + 4);
        short8 r;
        r[0] = (short)f2b(a[0]); r[1] = (short)f2b(a[1]);
        r[2] = (short)f2b(a[2]); r[3] = (short)f2b(a[3]);
        r[4] = (short)f2b(c[0]); r[5] = (short)f2b(c[1]);
        r[6] = (short)f2b(c[2]); r[7] = (short)f2b(c[3]);
        *(short8*)(dst + i * 8) = r;
    }
}

__global__ void convert_all_kernel(const void* __restrict__ emb_src, unsigned short* __restrict__ emb_dst,
                                   long n8, int nEmb,
                                   const void* __restrict__ gw_src, unsigned short* __restrict__ gw_dst,
                                   long gw8,
                                   const void* __restrict__ w1_src, unsigned short* __restrict__ w1_dst,
                                   long w18,
                                   TinyTensors tt) {
    __shared__ int isbfS;
    if (threadIdx.x == 0) isbfS = detect_bf16((const unsigned short*)emb_src) ? 1 : 0;
    __syncthreads();
    const bool isbf = (isbfS != 0);
    const int bid = blockIdx.x;

    if (bid < nEmb) {
        const long i = (long)bid * 256 + threadIdx.x;
        if (i < n8) conv_chunk(emb_src, emb_dst, i, isbf);
    } else if (bid < nEmb + 20) {
        const long q = (long)(bid - nEmb) * 256 + threadIdx.x;   // gw8+w18 = 5120 chunks
        if (q < gw8) conv_chunk(gw_src, gw_dst, q, isbf);
        else if (q < gw8 + w18) conv_chunk(w1_src, w1_dst, q - gw8, isbf);
    } else {
#pragma unroll
        for (int ti = 0; ti < 6; ++ti) {
            const int n = tt.n[ti];
            for (int i = threadIdx.x; i < n; i += 256) {
                const float v = isbf ? b2f(((const unsigned short*)tt.src[ti])[i])
                                     : ((const float*)tt.src[ti])[i];
                tt.dst[ti][i] = f2b(v);
            }
        }
    }
}

// ---------------- main kernel ----------------
// __launch_bounds__(256, 4): (256,5) forces the <=64-VGPR wave bucket (m69) ->
// massive scratch spills (r4/r5: WRITE 87/290 MB). 4 blocks/CU, LDS not binding.
// r7 changes: (a) gather split into independent conn-pass + emb-pass (r6's
// rolled loop was a ~6x serial (conn->emb) dependent chain = 23.7 us/round);
// (b) scores computed in P1 epilogue from fp32 acc (removes the P2 phase +
// one barrier); (c) W1/b1/w2 loads moved into P3 (off the P1 pressure peak).

__global__ __launch_bounds__(256, 4)
void embed_matcher_fast(const int* __restrict__ entity, const int* __restrict__ conn,
                        const unsigned short* __restrict__ emb,   // bf16 staged
                        const unsigned short* __restrict__ gw,
                        const unsigned short* __restrict__ gwb,
                        const unsigned short* __restrict__ gcnb,
                        const unsigned short* __restrict__ w1,
                        const unsigned short* __restrict__ b1,
                        const unsigned short* __restrict__ w2,
                        const unsigned short* __restrict__ b2,
                        const unsigned short* __restrict__ temp,
                        const void* __restrict__ emb_raw,         // for output-dtype probe
                        void* __restrict__ out)
{
    // Union buffer: phase 1 = X tile, 51 rows x XSTR (rows 0..49 data, row 50 zeros);
    // phase 2 (after barrier, X dead) = nbr tile, 64 rows x NSTR.
    __shared__ __align__(16) unsigned short XNs[(ZROW + 1) * XSTR];  // 26928 B
    __shared__ float selfE[EMBED_D];
    __shared__ float scoresS[MROWS];
    __shared__ float attnS[MROWS];
    __shared__ float gsumS[MROWS];
    __shared__ int flagS;

    const int t = threadIdx.x;
    const int b = blockIdx.x;
    const int lane = t & 63;
    const int wave = t >> 6;
    const int l15 = lane & 15;
    const int quad = lane >> 4;

    // ---- P0: B fragments into registers (NT-GEMM layout, m92/m97-verified) ----
    short8 Bfrag[8][2];
#pragma unroll
    for (int ft = 0; ft < 8; ++ft)
#pragma unroll
        for (int nn = 0; nn < 2; ++nn) {
            const int dcol = wave * 32 + nn * 16 + l15;
            Bfrag[ft][nn] = *(const short8*)(gw + dcol * 256 + ft * 32 + quad * 8);
        }

    // ---- P0b: gather, two independent passes (kill the conn->emb serial chain) ----
    {
        const int cbase = b * (KNBR * 2);
        int syms[7];
#pragma unroll
        for (int i = 0; i < 7; ++i) {
            const int c = t + 256 * i;
            syms[i] = (c < KNBR * 2 * 16) ? conn[cbase + (c >> 4)] : 0;
        }
#pragma unroll
        for (int i = 0; i < 7; ++i) {
            const int c = t + 256 * i;
            if (c < KNBR * 2 * 16) {
                const int r = c >> 4, j = c & 15;        // r = k*2 + half
                const short8 v = *(const short8*)(emb + (long)syms[i] * EMBED_D + j * 8);
                *(short8*)(XNs + (r >> 1) * XSTR + (r & 1) * 128 + j * 8) = v;
            }
        }
        const short8 z8 = {0, 0, 0, 0, 0, 0, 0, 0};
        if (t < 33)                                      // 528 B zero row
            *(short8*)(XNs + ZROW * XSTR + t * 8) = z8;
        if (t < EMBED_D) selfE[t] = b2f(emb[(long)entity[b] * EMBED_D + t]);
        if (t < MROWS) {
            gsumS[t] = b2f(b2[0]);                       // gate logit accumulator init
            scoresS[t] = 0.f;                            // score accumulator init
        }
        if (t == 0) flagS = detect_bf16((const unsigned short*)emb_raw) ? 1 : 0;
    }
    __syncthreads();

    // ---- P1: nbr = X(64x256) . W^T via mfma_f32_16x16x32_bf16 ----
    const int r3 = 48 + l15;
    const int row3 = (r3 < KNBR) ? r3 : ZROW;            // m=3 tail rows -> shared zero row

    floatx4 acc[4][2];
    const floatx4 fzero = {0.f, 0.f, 0.f, 0.f};
#pragma unroll
    for (int m = 0; m < 4; ++m)
#pragma unroll
        for (int nn = 0; nn < 2; ++nn) acc[m][nn] = fzero;
#pragma unroll
    for (int ft = 0; ft < 8; ++ft) {
        const int cofs = ft * 32 + quad * 8;
        short8 A[4];
#pragma unroll
        for (int m = 0; m < 3; ++m)
            A[m] = *(const short8*)(XNs + (m * 16 + l15) * XSTR + cofs);
        A[3] = *(const short8*)(XNs + row3 * XSTR + cofs);
#pragma unroll
        for (int m = 0; m < 4; ++m)
#pragma unroll
            for (int nn = 0; nn < 2; ++nn)
                acc[m][nn] = __builtin_amdgcn_mfma_f32_16x16x32_bf16(A[m], Bfrag[ft][nn], acc[m][nn], 0, 0, 0);
    }
    __syncthreads();   // X region dead; reuse XNs as the nbr tile

    // ---- P1 epilogue: bias + Ns store (bf16) + scores from fp32 acc ----
    // C/D layout: row = m*16 + quad*4 + r, col = wave*32 + nn*16 + l15.
    {
        const int dcol0 = wave * 32 + l15;
        const int dcol1 = dcol0 + 16;
        const float bias0 = b2f(gwb[dcol0]);
        const float bias1 = b2f(gwb[dcol1]);
        const float se0 = selfE[dcol0];
        const float se1 = selfE[dcol1];
#pragma unroll
        for (int m = 0; m < 4; ++m)
#pragma unroll
            for (int r = 0; r < 4; ++r) {
                const int row = m * 16 + quad * 4 + r;
                const float v0 = acc[m][0][r] + bias0;
                const float v1 = acc[m][1][r] + bias1;
                XNs[row * NSTR + dcol0] = f2b(v0);
                XNs[row * NSTR + dcol1] = f2b(v1);
                float p = se0 * v0 + se1 * v1;           // partial over this lane's 2 cols
                p += __shfl_xor(p, 1);                   // reduce across the 16 l15 lanes
                p += __shfl_xor(p, 2);
                p += __shfl_xor(p, 4);
                p += __shfl_xor(p, 8);
                if (l15 == 0) atomicAdd(&scoresS[row], p);
            }
    }
    __syncthreads();

    // ---- softmax over k (wave 0; other waves fall through to P3) ----
    if (t < 64) {
        const float s = (t < KNBR) ? scoresS[t] * 0.088388347648318447f : -INFINITY;  // /sqrt(128)
        float mx = s;
#pragma unroll
        for (int o = 32; o > 0; o >>= 1) mx = fmaxf(mx, __shfl_xor(mx, o));
        const float e = (t < KNBR) ? expf(s - mx) : 0.f;
        float sum = e;
#pragma unroll
        for (int o = 32; o > 0; o >>= 1) sum += __shfl_xor(sum, o);
        attnS[t] = e / sum;
    }

    // ---- P3: gate MLP: h = relu(nbr.w1^T + b1); logit = h.w2 ----
    const float b1j = b2f(b1[wave * 16 + l15]);
    const float w2j = b2f(w2[wave * 16 + l15]);
    floatx4 acc2[4];
#pragma unroll
    for (int m = 0; m < 4; ++m) acc2[m] = fzero;
#pragma unroll
    for (int ft = 0; ft < 4; ++ft) {
        const short8 W1 = *(const short8*)(w1 + (wave * 16 + l15) * 128 + ft * 32 + quad * 8);
        short8 A2[4];
#pragma unroll
        for (int m = 0; m < 4; ++m)
            A2[m] = *(const short8*)(XNs + (m * 16 + l15) * NSTR + ft * 32 + quad * 8);
#pragma unroll
        for (int m = 0; m < 4; ++m)
            acc2[m] = __builtin_amdgcn_mfma_f32_16x16x32_bf16(A2[m], W1, acc2[m], 0, 0, 0);
    }
#pragma unroll
    for (int m = 0; m < 4; ++m)
#pragma unroll
        for (int r = 0; r < 4; ++r) {
            float c = fmaxf(acc2[m][r] + b1j, 0.f) * w2j;
            c += __shfl_xor(c, 1);   // sum the 16 h-cols held across l15
            c += __shfl_xor(c, 2);
            c += __shfl_xor(c, 4);
            c += __shfl_xor(c, 8);
            if (l15 == 0) atomicAdd(&gsumS[m * 16 + quad * 4 + r], c);
        }
    __syncthreads();

    // ---- P4a: fold gate into attn ----
    if (t < KNBR) {
        const float invT = 1.0f / b2f(temp[0]);
        const float g = 1.0f / (1.0f + expf(-gsumS[t] * invT));
        attnS[t] *= g;
    }
    __syncthreads();

    // ---- P4b: out[d] = tanh(max_k(attn*gate*nbr) + gcn_b) ----
    if (t < EMBED_D) {
        float mx = -INFINITY;
#pragma unroll
        for (int k = 0; k < KNBR; ++k)
            mx = fmaxf(mx, attnS[k] * b2f(XNs[k * NSTR + t]));
        const float o = tanhf(mx + b2f(gcnb[t]));
        if (flagS)
            ((unsigned short*)out)[(long)b * EMBED_D + t] = f2b(o);
        else
            ((float*)out)[(long)b * EMBED_D + t] = o;
    }
}

// ---------------- fallback (round-2 proven kernel, used only if ws too small) ----------------

template <bool BF16IN>
__device__ __forceinline__ short8 load8g(const void* base, long off) {
    if constexpr (BF16IN) {
        return *(const short8*)((const unsigned short*)base + off);
    } else {
        const float* p = (const float*)base + off;
        const floatx4 a = *(const floatx4*)p;
        const floatx4 c = *(const floatx4*)(p + 4);
        short8 r;
        r[0] = (short)f2b(a[0]); r[1] = (short)f2b(a[1]);
        r[2] = (short)f2b(a[2]); r[3] = (short)f2b(a[3]);
        r[4] = (short)f2b(c[0]); r[5] = (short)f2b(c[1]);
        r[6] = (short)f2b(c[2]); r[7] = (short)f2b(c[3]);
        return r;
    }
}
template <bool BF16IN>
__device__ __forceinline__ float loadSg(const void* base, long off) {
    if constexpr (BF16IN) return b2f(((const unsigned short*)base)[off]);
    else return ((const float*)base)[off];
}

template <bool BF16IN>
__device__ __forceinline__ void body_fb(
    const int* entity, const int* conn, const void* emb, const void* gw,
    const void* gwb, const void* gcnb, const void* w1, const void* b1,
    const void* w2, const void* b2, const void* temp, void* out,
    unsigned short* Xs, unsigned short* Ns,
    float* selfE, float* scoresS, float* attnS, float* gsumS)
{
    const int t = threadIdx.x, b = blockIdx.x;
    const int lane = t & 63, wave = t >> 6, l15 = lane & 15, quad = lane >> 4;
    short8 Bfrag[8][2];
#pragma unroll
    for (int ft = 0; ft < 8; ++ft)
#pragma unroll
        for (int nn = 0; nn < 2; ++nn)
            Bfrag[ft][nn] = load8g<BF16IN>(gw, (wave * 32 + nn * 16 + l15) * 256 + ft * 32 + quad * 8);
    short8 W1frag[4];
#pragma unroll
    for (int ft = 0; ft < 4; ++ft)
        W1frag[ft] = load8g<BF16IN>(w1, (wave * 16 + l15) * 128 + ft * 32 + quad * 8);
    const float b1j = loadSg<BF16IN>(b1, wave * 16 + l15);
    const float w2j = loadSg<BF16IN>(w2, wave * 16 + l15);
    {
        const int cbase = b * (KNBR * 2);
        for (int c = t; c < KNBR * 2 * 16; c += 256) {
            const int r = c >> 4, j = c & 15;
            const int sym = conn[cbase + r];
            *(short8*)(Xs + (r >> 1) * XSTR + (r & 1) * 128 + j * 8) =
                load8g<BF16IN>(emb, (long)sym * EMBED_D + j * 8);
        }
        for (int i = t; i < (MROWS - KNBR) * 256; i += 256)
            Xs[(KNBR + (i >> 8)) * XSTR + (i & 255)] = 0;
        if (t < EMBED_D) selfE[t] = loadSg<BF16IN>(emb, (long)entity[b] * EMBED_D + t);
        if (t < MROWS) gsumS[t] = loadSg<BF16IN>(b2, 0);
    }
    __syncthreads();
    floatx4 acc[4][2];
    const floatx4 fzero = {0.f, 0.f, 0.f, 0.f};
#pragma unroll
    for (int m = 0; m < 4; ++m)
#pragma unroll
        for (int nn = 0; nn < 2; ++nn) acc[m][nn] = fzero;
#pragma unroll
    for (int ft = 0; ft < 8; ++ft) {
        short8 A[4];
#pragma unroll
        for (int m = 0; m < 4; ++m)
            A[m] = *(const short8*)(Xs + (m * 16 + l15) * XSTR + ft * 32 + quad * 8);
#pragma unroll
        for (int m = 0; m < 4; ++m)
#pragma unroll
            for (int nn = 0; nn < 2; ++nn)
                acc[m][nn] = __builtin_amdgcn_mfma_f32_16x16x32_bf16(A[m], Bfrag[ft][nn], acc[m][nn], 0, 0, 0);
    }
#pragma unroll
    for (int nn = 0; nn < 2; ++nn) {
        const int dcol = wave * 32 + nn * 16 + l15;
        const float bias = loadSg<BF16IN>(gwb, dcol);
#pragma unroll
        for (int m = 0; m < 4; ++m)
#pragma unroll
            for (int r = 0; r < 4; ++r)
                Ns[(m * 16 + quad * 4 + r) * NSTR + dcol] = f2b(acc[m][nn][r] + bias);
    }
    __syncthreads();
    {
        const int k = t >> 2, q = t & 3;
        float p = 0.f;
        if (k < KNBR) {
            const unsigned short* nr = Ns + k * NSTR + q * 32;
            const float* se = selfE + q * 32;
#pragma unroll
            for (int i = 0; i < 32; ++i) p += se[i] * b2f(nr[i]);
        }
        p += __shfl_xor(p, 1);
        p += __shfl_xor(p, 2);
        if (k < KNBR && q == 0) scoresS[k] = p * 0.088388347648318447f;
    }
    __syncthreads();
    if (t < 64) {
        const float s = (t < KNBR) ? scoresS[t] : -INFINITY;
        float mx = s;
#pragma unroll
        for (int o = 32; o > 0; o >>= 1) mx = fmaxf(mx, __shfl_xor(mx, o));
        const float e = (t < KNBR) ? expf(s - mx) : 0.f;
        float sum = e;
#pragma unroll
        for (int o = 32; o > 0; o >>= 1) sum += __shfl_xor(sum, o);
        attnS[t] = e / sum;
    }
    floatx4 acc2[4];
#pragma unroll
    for (int m = 0; m < 4; ++m) acc2[m] = fzero;
#pragma unroll
    for (int ft = 0; ft < 4; ++ft) {
        short8 A2[4];
#pragma unroll
        for (int m = 0; m < 4; ++m)
            A2[m] = *(const short8*)(Ns + (m * 16 + l15) * NSTR + ft * 32 + quad * 8);
#pragma unroll
        for (int m = 0; m < 4; ++m)
            acc2[m] = __builtin_amdgcn_mfma_f32_16x16x32_bf16(A2[m], W1frag[ft], acc2[m], 0, 0, 0);
    }
#pragma unroll
    for (int m = 0; m < 4; ++m)
#pragma unroll
        for (int r = 0; r < 4; ++r) {
            float c = fmaxf(acc2[m][r] + b1j, 0.f) * w2j;
            c += __shfl_xor(c, 1); c += __shfl_xor(c, 2);
            c += __shfl_xor(c, 4); c += __shfl_xor(c, 8);
            if (l15 == 0) atomicAdd(&gsumS[m * 16 + quad * 4 + r], c);
        }
    __syncthreads();
    if (t < KNBR) {
        const float invT = 1.0f / loadSg<BF16IN>(temp, 0);
        attnS[t] *= 1.0f / (1.0f + expf(-gsumS[t] * invT));
    }
    __syncthreads();
    if (t < EMBED_D) {
        float mx = -INFINITY;
        for (int k = 0; k < KNBR; ++k)
            mx = fmaxf(mx, attnS[k] * b2f(Ns[k * NSTR + t]));
        const float o = tanhf(mx + loadSg<BF16IN>(gcnb, t));
        if constexpr (BF16IN)
            ((unsigned short*)out)[(long)b * EMBED_D + t] = f2b(o);
        else
            ((float*)out)[(long)b * EMBED_D + t] = o;
    }
}

__global__ __launch_bounds__(256, 2)
void embed_matcher_fallback(const int* entity, const int* conn, const void* emb,
                            const void* gw, const void* gwb, const void* gcnb,
                            const void* w1, const void* b1, const void* w2,
                            const void* b2, const void* temp, void* out)
{
    __shared__ __align__(16) unsigned short Xs[MROWS * XSTR];
    __shared__ __align__(16) unsigned short Ns[MROWS * NSTR];
    __shared__ float selfE[EMBED_D];
    __shared__ float scoresS[MROWS];
    __shared__ float attnS[MROWS];
    __shared__ float gsumS[MROWS];
    if (detect_bf16((const unsigned short*)emb))
        body_fb<true>(entity, conn, emb, gw, gwb, gcnb, w1, b1, w2, b2, temp, out,
                      Xs, Ns, selfE, scoresS, attnS, gsumS);
    else
        body_fb<false>(entity, conn, emb, gw, gwb, gcnb, w1, b1, w2, b2, temp, out,
                       Xs, Ns, selfE, scoresS, attnS, gsumS);
}

// ---------------- launcher ----------------

static inline size_t align256(size_t x) { return (x + 255) & ~(size_t)255; }

extern "C" void kernel_launch(void* const* d_in, const int* in_sizes, int n_in,
                              void* d_out, int out_size, void* d_ws, size_t ws_size,
                              hipStream_t stream) {
    (void)n_in; (void)out_size;
    const int B = in_sizes[0];  // 8192

    // ws layout: bf16 copies of all float tensors
    const long n_emb = in_sizes[2];
    size_t off[9], cur = 0;
    const int ns[8] = {in_sizes[3], in_sizes[4], in_sizes[5], in_sizes[6],
                       in_sizes[7], in_sizes[8], in_sizes[9], in_sizes[10]};
    off[0] = 0; cur = align256((size_t)n_emb * 2);                      // emb
    for (int i = 0; i < 8; ++i) { off[i + 1] = cur; cur = align256(cur + (size_t)ns[i] * 2); }

    if (ws_size < cur) {
        embed_matcher_fallback<<<B, 256, 0, stream>>>(
            (const int*)d_in[0], (const int*)d_in[1],
            d_in[2], d_in[3], d_in[4], d_in[5],
            d_in[6], d_in[7], d_in[8], d_in[9], d_in[10], d_out);
        return;
    }

    char* ws = (char*)d_ws;
    unsigned short* emb_b = (unsigned short*)(ws + off[0]);

    // tiny tensors: gwb, gcnb, b1, w2, b2, temp  (input idx 4,5,7,8,9,10)
    TinyTensors tt;
    const int tin[6] = {4, 5, 7, 8, 9, 10};
    for (int i = 0; i < 6; ++i) {
        tt.src[i] = d_in[tin[i]];
        tt.dst[i] = (unsigned short*)(ws + off[tin[i] - 2]);
        tt.n[i] = in_sizes[tin[i]];
    }

    const long n8 = n_emb / 8;                     // 1,600,016 chunks
    const int nEmb = (int)((n8 + 255) / 256);      // 6251 blocks
    const long gw8 = in_sizes[3] / 8;              // 4096 chunks
    const long w18 = in_sizes[6] / 8;              // 1024 chunks
    convert_all_kernel<<<nEmb + 20 + 1, 256, 0, stream>>>(
        d_in[2], emb_b, n8, nEmb,
        d_in[3], (unsigned short*)(ws + off[1]), gw8,
        d_in[6], (unsigned short*)(ws + off[4]), w18,
        tt);

    embed_matcher_fast<<<B, 256, 0, stream>>>(
        (const int*)d_in[0], (const int*)d_in[1],
        emb_b,
        (const unsigned short*)(ws + off[1]),   // gw
        (const unsigned short*)(ws + off[2]),   // gwb
        (const unsigned short*)(ws + off[3]),   // gcnb
        (const unsigned short*)(ws + off[4]),   // w1
        (const unsigned short*)(ws + off[5]),   // b1
        (const unsigned short*)(ws + off[6]),   // w2
        (const unsigned short*)(ws + off[7]),   // b2
        (const unsigned short*)(ws + off[8]),   // temp
        d_in[2],                                // raw emb for dtype probe
        d_out);
}

// Round 8
// 283.896 us; speedup vs baseline: 1.4048x; 1.0037x over previous
//
#include <hip/hip_runtime.h>

#define EMBED_D 128
#define KNBR 50
#define STR 136       // unified LDS row stride (128 + 8 pad; 272 B = 4 banks mod 32 -> 2-way = free)
#define ZROW 50       // all-zero X row for m=3 tail lanes
#define XSTR 264      // (fallback only)
#define NSTR 136      // (fallback only)
#define MROWS 64

typedef __attribute__((ext_vector_type(8))) short short8;    // 8 bf16 = 4 VGPRs (MFMA A/B frag)
typedef __attribute__((ext_vector_type(4))) float floatx4;   // MFMA C/D frag

__device__ __forceinline__ float b2f(unsigned short u) {
    union { unsigned int i; float f; } v;
    v.i = ((unsigned int)u) << 16;
    return v.f;
}
__device__ __forceinline__ unsigned short f2b(float f) {
    union { float f; unsigned int i; } v;
    v.f = f;
    return (unsigned short)((v.i + 0x7fffu + ((v.i >> 16) & 1u)) >> 16);  // RNE, finite-only
}

// bf16 emb data (N(0,0.02)) decodes to |v| < 0.15 everywhere; fp32 data has
// random low-mantissa words -> some finite |v| >= 1.0 with P ~ 1-2e-10.
__device__ __forceinline__ bool detect_bf16(const unsigned short* p) {
    float mx = 0.f;
#pragma unroll
    for (int i = 0; i < 64; ++i) {
        const float a = fabsf(b2f(p[i]));
        if (a < 3.0e38f && a > mx) mx = a;
    }
    return mx < 1.0f;
}

// ---------------- preprocessing (r7 straggler-free version, unchanged) ----------------

struct TinyTensors {
    const void* src[6];
    unsigned short* dst[6];
    int n[6];
};

__device__ __forceinline__ void conv_chunk(const void* src, unsigned short* dst,
                                           long i, bool isbf) {
    if (isbf) {
        *(short8*)(dst + i * 8) = *(const short8*)((const unsigned short*)src + i * 8);
    } else {
        const float* p = (const float*)src + i * 8;
        const floatx4 a = *(const floatx4*)p;
        const floatx4 c = *(const floatx4*)(p + 4);
        short8 r;
        r[0] = (short)f2b(a[0]); r[1] = (short)f2b(a[1]);
        r[2] = (short)f2b(a[2]); r[3] = (short)f2b(a[3]);
        r[4] = (short)f2b(c[0]); r[5] = (short)f2b(c[1]);
        r[6] = (short)f2b(c[2]); r[7] = (short)f2b(c[3]);
        *(short8*)(dst + i * 8) = r;
    }
}

__global__ void convert_all_kernel(const void* __restrict__ emb_src, unsigned short* __restrict__ emb_dst,
                                   long n8, int nEmb,
                                   const void* __restrict__ gw_src, unsigned short* __restrict__ gw_dst,
                                   long gw8,
                                   const void* __restrict__ w1_src, unsigned short* __restrict__ w1_dst,
                                   long w18,
                                   TinyTensors tt) {
    __shared__ int isbfS;
    if (threadIdx.x == 0) isbfS = detect_bf16((const unsigned short*)emb_src) ? 1 : 0;
    __syncthreads();
    const bool isbf = (isbfS != 0);
    const int bid = blockIdx.x;

    if (bid < nEmb) {
        const long i = (long)bid * 256 + threadIdx.x;
        if (i < n8) conv_chunk(emb_src, emb_dst, i, isbf);
    } else if (bid < nEmb + 20) {
        const long q = (long)(bid - nEmb) * 256 + threadIdx.x;
        if (q < gw8) conv_chunk(gw_src, gw_dst, q, isbf);
        else if (q < gw8 + w18) conv_chunk(w1_src, w1_dst, q - gw8, isbf);
    } else {
#pragma unroll
        for (int ti = 0; ti < 6; ++ti) {
            const int n = tt.n[ti];
            for (int i = threadIdx.x; i < n; i += 256) {
                const float v = isbf ? b2f(((const unsigned short*)tt.src[ti])[i])
                                     : ((const float*)tt.src[ti])[i];
                tt.dst[ti][i] = f2b(v);
            }
        }
    }
}

// ---------------- main kernel: K-split, 18.7 KB LDS, <=64-VGPR bucket ----------------
// K=256 GEMM split into two K=128 halves sharing ONE 64x136 tile (X half1 ->
// X half2 -> Ns). LDS 28.7 -> ~18.7 KB: LDS was the residency binder (r7:
// ~3.4 blocks/CU, per-block latency ~20 us >> ~2 us compute).
// __launch_bounds__(256,8): pins allocator into the <=64-VGPR bucket (m69:
// waves/CU halve at 64/128/256; r7 measured 60 VGPR). If WRITE_SIZE >> 4 MB,
// this spilled -> revert to (256,4).

__global__ __launch_bounds__(256, 8)
void embed_matcher_fast(const int* __restrict__ entity, const int* __restrict__ conn,
                        const unsigned short* __restrict__ emb,   // bf16 staged
                        const unsigned short* __restrict__ gw,
                        const unsigned short* __restrict__ gwb,
                        const unsigned short* __restrict__ gcnb,
                        const unsigned short* __restrict__ w1,
                        const unsigned short* __restrict__ b1,
                        const unsigned short* __restrict__ w2,
                        const unsigned short* __restrict__ b2,
                        const unsigned short* __restrict__ temp,
                        const void* __restrict__ emb_raw,         // for output-dtype probe
                        void* __restrict__ out)
{
    __shared__ __align__(16) unsigned short XNs[MROWS * STR];  // 17408 B, triple-reused
    __shared__ float selfE[EMBED_D];
    __shared__ float scoresS[MROWS];
    __shared__ float attnS[MROWS];
    __shared__ float gsumS[MROWS];
    __shared__ int flagS;

    const int t = threadIdx.x;
    const int b = blockIdx.x;
    const int lane = t & 63;
    const int wave = t >> 6;
    const int l15 = lane & 15;
    const int quad = lane >> 4;
    const int cbase = b * (KNBR * 2);

    const int r3row = 48 + l15;
    const int row3 = (r3row < KNBR) ? r3row : ZROW;      // m=3 tail -> shared zero row

    floatx4 acc[4][2];
    const floatx4 fzero = {0.f, 0.f, 0.f, 0.f};
#pragma unroll
    for (int m = 0; m < 4; ++m)
#pragma unroll
        for (int nn = 0; nn < 2; ++nn) acc[m][nn] = fzero;

    // ---- P0: gather half 0 (rel) + block setup ----
    {
        int syms[4];
#pragma unroll
        for (int i = 0; i < 4; ++i) {
            const int c = t + 256 * i;                   // c = k*16 + j, 800 chunks
            syms[i] = (c < KNBR * 16) ? conn[cbase + ((c >> 4) << 1)] : 0;
        }
#pragma unroll
        for (int i = 0; i < 4; ++i) {
            const int c = t + 256 * i;
            if (c < KNBR * 16) {
                const short8 v = *(const short8*)(emb + (long)syms[i] * EMBED_D + (c & 15) * 8);
                *(short8*)(XNs + (c >> 4) * STR + (c & 15) * 8) = v;
            }
        }
        const short8 z8 = {0, 0, 0, 0, 0, 0, 0, 0};
        if (t < 17)                                      // zero row: 136 elems = 17 chunks
            *(short8*)(XNs + ZROW * STR + t * 8) = z8;
        if (t < EMBED_D) selfE[t] = b2f(emb[(long)entity[b] * EMBED_D + t]);
        if (t < MROWS) {
            gsumS[t] = b2f(b2[0]);
            scoresS[t] = 0.f;
        }
        if (t == 0) flagS = detect_bf16((const unsigned short*)emb_raw) ? 1 : 0;
    }
    __syncthreads();

    // ---- P1a: accumulate rel half (k = 0..127) ----
#pragma unroll
    for (int ft = 0; ft < 4; ++ft) {
        const int cofs = ft * 32 + quad * 8;
        short8 A[4];
#pragma unroll
        for (int m = 0; m < 3; ++m)
            A[m] = *(const short8*)(XNs + (m * 16 + l15) * STR + cofs);
        A[3] = *(const short8*)(XNs + row3 * STR + cofs);
#pragma unroll
        for (int m = 0; m < 4; ++m)
#pragma unroll
            for (int nn = 0; nn < 2; ++nn) {
                const short8 B = *(const short8*)(gw + (wave * 32 + nn * 16 + l15) * 256 + cofs);
                acc[m][nn] = __builtin_amdgcn_mfma_f32_16x16x32_bf16(A[m], B, acc[m][nn], 0, 0, 0);
            }
    }
    __syncthreads();   // all waves done reading X half 0

    // ---- P0c: gather half 1 (ent) into the same tile ----
    {
        int syms[4];
#pragma unroll
        for (int i = 0; i < 4; ++i) {
            const int c = t + 256 * i;
            syms[i] = (c < KNBR * 16) ? conn[cbase + ((c >> 4) << 1) + 1] : 0;
        }
#pragma unroll
        for (int i = 0; i < 4; ++i) {
            const int c = t + 256 * i;
            if (c < KNBR * 16) {
                const short8 v = *(const short8*)(emb + (long)syms[i] * EMBED_D + (c & 15) * 8);
                *(short8*)(XNs + (c >> 4) * STR + (c & 15) * 8) = v;
            }
        }
        // row ZROW untouched -> stays zero
    }
    __syncthreads();

    // ---- P1b: accumulate ent half (k = 128..255) ----
#pragma unroll
    for (int ft = 0; ft < 4; ++ft) {
        const int cofs = ft * 32 + quad * 8;
        short8 A[4];
#pragma unroll
        for (int m = 0; m < 3; ++m)
            A[m] = *(const short8*)(XNs + (m * 16 + l15) * STR + cofs);
        A[3] = *(const short8*)(XNs + row3 * STR + cofs);
#pragma unroll
        for (int m = 0; m < 4; ++m)
#pragma unroll
            for (int nn = 0; nn < 2; ++nn) {
                const short8 B = *(const short8*)(gw + (wave * 32 + nn * 16 + l15) * 256 + 128 + cofs);
                acc[m][nn] = __builtin_amdgcn_mfma_f32_16x16x32_bf16(A[m], B, acc[m][nn], 0, 0, 0);
            }
    }
    __syncthreads();   // X dead; reuse XNs as the nbr tile

    // ---- P1 epilogue: bias + Ns store (bf16) + scores from fp32 acc ----
    // C/D layout: row = m*16 + quad*4 + r, col = wave*32 + nn*16 + l15.
    {
        const int dcol0 = wave * 32 + l15;
        const int dcol1 = dcol0 + 16;
        const float bias0 = b2f(gwb[dcol0]);
        const float bias1 = b2f(gwb[dcol1]);
        const float se0 = selfE[dcol0];
        const float se1 = selfE[dcol1];
#pragma unroll
        for (int m = 0; m < 4; ++m)
#pragma unroll
            for (int r = 0; r < 4; ++r) {
                const int row = m * 16 + quad * 4 + r;
                const float v0 = acc[m][0][r] + bias0;
                const float v1 = acc[m][1][r] + bias1;
                XNs[row * STR + dcol0] = f2b(v0);
                XNs[row * STR + dcol1] = f2b(v1);
                float p = se0 * v0 + se1 * v1;
                p += __shfl_xor(p, 1);                   // reduce across the 16 l15 lanes
                p += __shfl_xor(p, 2);
                p += __shfl_xor(p, 4);
                p += __shfl_xor(p, 8);
                if (l15 == 0) atomicAdd(&scoresS[row], p);
            }
    }
    __syncthreads();

    // ---- softmax over k (wave 0; other waves fall through to P3) ----
    if (t < 64) {
        const float s = (t < KNBR) ? scoresS[t] * 0.088388347648318447f : -INFINITY;  // /sqrt(128)
        float mx = s;
#pragma unroll
        for (int o = 32; o > 0; o >>= 1) mx = fmaxf(mx, __shfl_xor(mx, o));
        const float e = (t < KNBR) ? expf(s - mx) : 0.f;
        float sum = e;
#pragma unroll
        for (int o = 32; o > 0; o >>= 1) sum += __shfl_xor(sum, o);
        attnS[t] = e / sum;
    }

    // ---- P3: gate MLP: h = relu(nbr.w1^T + b1); logit = h.w2 ----
    // Rows 50..63 of the nbr tile hold stale-but-finite data; their logits land
    // in gsumS[50..63], which is never read (k < 50).
    const float b1j = b2f(b1[wave * 16 + l15]);
    const float w2j = b2f(w2[wave * 16 + l15]);
    floatx4 acc2[4];
#pragma unroll
    for (int m = 0; m < 4; ++m) acc2[m] = fzero;
#pragma unroll
    for (int ft = 0; ft < 4; ++ft) {
        const short8 W1 = *(const short8*)(w1 + (wave * 16 + l15) * 128 + ft * 32 + quad * 8);
        short8 A2[4];
#pragma unroll
        for (int m = 0; m < 4; ++m)
            A2[m] = *(const short8*)(XNs + (m * 16 + l15) * STR + ft * 32 + quad * 8);
#pragma unroll
        for (int m = 0; m < 4; ++m)
            acc2[m] = __builtin_amdgcn_mfma_f32_16x16x32_bf16(A2[m], W1, acc2[m], 0, 0, 0);
    }
#pragma unroll
    for (int m = 0; m < 4; ++m)
#pragma unroll
        for (int r = 0; r < 4; ++r) {
            float c = fmaxf(acc2[m][r] + b1j, 0.f) * w2j;
            c += __shfl_xor(c, 1);
            c += __shfl_xor(c, 2);
            c += __shfl_xor(c, 4);
            c += __shfl_xor(c, 8);
            if (l15 == 0) atomicAdd(&gsumS[m * 16 + quad * 4 + r], c);
        }
    __syncthreads();

    // ---- P4a: fold gate into attn ----
    if (t < KNBR) {
        const float invT = 1.0f / b2f(temp[0]);
        const float g = 1.0f / (1.0f + expf(-gsumS[t] * invT));
        attnS[t] *= g;
    }
    __syncthreads();

    // ---- P4b: out[d] = tanh(max_k(attn*gate*nbr) + gcn_b) ----
    if (t < EMBED_D) {
        float mx = -INFINITY;
#pragma unroll
        for (int k = 0; k < KNBR; ++k)
            mx = fmaxf(mx, attnS[k] * b2f(XNs[k * STR + t]));
        const float o = tanhf(mx + b2f(gcnb[t]));
        if (flagS)
            ((unsigned short*)out)[(long)b * EMBED_D + t] = f2b(o);
        else
            ((float*)out)[(long)b * EMBED_D + t] = o;
    }
}

// ---------------- fallback (round-2 proven kernel, used only if ws too small) ----------------

template <bool BF16IN>
__device__ __forceinline__ short8 load8g(const void* base, long off) {
    if constexpr (BF16IN) {
        return *(const short8*)((const unsigned short*)base + off);
    } else {
        const float* p = (const float*)base + off;
        const floatx4 a = *(const floatx4*)p;
        const floatx4 c = *(const floatx4*)(p + 4);
        short8 r;
        r[0] = (short)f2b(a[0]); r[1] = (short)f2b(a[1]);
        r[2] = (short)f2b(a[2]); r[3] = (short)f2b(a[3]);
        r[4] = (short)f2b(c[0]); r[5] = (short)f2b(c[1]);
        r[6] = (short)f2b(c[2]); r[7] = (short)f2b(c[3]);
        return r;
    }
}
template <bool BF16IN>
__device__ __forceinline__ float loadSg(const void* base, long off) {
    if constexpr (BF16IN) return b2f(((const unsigned short*)base)[off]);
    else return ((const float*)base)[off];
}

template <bool BF16IN>
__device__ __forceinline__ void body_fb(
    const int* entity, const int* conn, const void* emb, const void* gw,
    const void* gwb, const void* gcnb, const void* w1, const void* b1,
    const void* w2, const void* b2, const void* temp, void* out,
    unsigned short* Xs, unsigned short* Ns,
    float* selfE, float* scoresS, float* attnS, float* gsumS)
{
    const int t = threadIdx.x, b = blockIdx.x;
    const int lane = t & 63, wave = t >> 6, l15 = lane & 15, quad = lane >> 4;
    short8 Bfrag[8][2];
#pragma unroll
    for (int ft = 0; ft < 8; ++ft)
#pragma unroll
        for (int nn = 0; nn < 2; ++nn)
            Bfrag[ft][nn] = load8g<BF16IN>(gw, (wave * 32 + nn * 16 + l15) * 256 + ft * 32 + quad * 8);
    short8 W1frag[4];
#pragma unroll
    for (int ft = 0; ft < 4; ++ft)
        W1frag[ft] = load8g<BF16IN>(w1, (wave * 16 + l15) * 128 + ft * 32 + quad * 8);
    const float b1j = loadSg<BF16IN>(b1, wave * 16 + l15);
    const float w2j = loadSg<BF16IN>(w2, wave * 16 + l15);
    {
        const int cbase = b * (KNBR * 2);
        for (int c = t; c < KNBR * 2 * 16; c += 256) {
            const int r = c >> 4, j = c & 15;
            const int sym = conn[cbase + r];
            *(short8*)(Xs + (r >> 1) * XSTR + (r & 1) * 128 + j * 8) =
                load8g<BF16IN>(emb, (long)sym * EMBED_D + j * 8);
        }
        for (int i = t; i < (MROWS - KNBR) * 256; i += 256)
            Xs[(KNBR + (i >> 8)) * XSTR + (i & 255)] = 0;
        if (t < EMBED_D) selfE[t] = loadSg<BF16IN>(emb, (long)entity[b] * EMBED_D + t);
        if (t < MROWS) gsumS[t] = loadSg<BF16IN>(b2, 0);
    }
    __syncthreads();
    floatx4 acc[4][2];
    const floatx4 fzero = {0.f, 0.f, 0.f, 0.f};
#pragma unroll
    for (int m = 0; m < 4; ++m)
#pragma unroll
        for (int nn = 0; nn < 2; ++nn) acc[m][nn] = fzero;
#pragma unroll
    for (int ft = 0; ft < 8; ++ft) {
        short8 A[4];
#pragma unroll
        for (int m = 0; m < 4; ++m)
            A[m] = *(const short8*)(Xs + (m * 16 + l15) * XSTR + ft * 32 + quad * 8);
#pragma unroll
        for (int m = 0; m < 4; ++m)
#pragma unroll
            for (int nn = 0; nn < 2; ++nn)
                acc[m][nn] = __builtin_amdgcn_mfma_f32_16x16x32_bf16(A[m], Bfrag[ft][nn], acc[m][nn], 0, 0, 0);
    }
#pragma unroll
    for (int nn = 0; nn < 2; ++nn) {
        const int dcol = wave * 32 + nn * 16 + l15;
        const float bias = loadSg<BF16IN>(gwb, dcol);
#pragma unroll
        for (int m = 0; m < 4; ++m)
#pragma unroll
            for (int r = 0; r < 4; ++r)
                Ns[(m * 16 + quad * 4 + r) * NSTR + dcol] = f2b(acc[m][nn][r] + bias);
    }
    __syncthreads();
    {
        const int k = t >> 2, q = t & 3;
        float p = 0.f;
        if (k < KNBR) {
            const unsigned short* nr = Ns + k * NSTR + q * 32;
            const float* se = selfE + q * 32;
#pragma unroll
            for (int i = 0; i < 32; ++i) p += se[i] * b2f(nr[i]);
        }
        p += __shfl_xor(p, 1);
        p += __shfl_xor(p, 2);
        if (k < KNBR && q == 0) scoresS[k] = p * 0.088388347648318447f;
    }
    __syncthreads();
    if (t < 64) {
        const float s = (t < KNBR) ? scoresS[t] : -INFINITY;
        float mx = s;
#pragma unroll
        for (int o = 32; o > 0; o >>= 1) mx = fmaxf(mx, __shfl_xor(mx, o));
        const float e = (t < KNBR) ? expf(s - mx) : 0.f;
        float sum = e;
#pragma unroll
        for (int o = 32; o > 0; o >>= 1) sum += __shfl_xor(sum, o);
        attnS[t] = e / sum;
    }
    floatx4 acc2[4];
#pragma unroll
    for (int m = 0; m < 4; ++m) acc2[m] = fzero;
#pragma unroll
    for (int ft = 0; ft < 4; ++ft) {
        short8 A2[4];
#pragma unroll
        for (int m = 0; m < 4; ++m)
            A2[m] = *(const short8*)(Ns + (m * 16 + l15) * NSTR + ft * 32 + quad * 8);
#pragma unroll
        for (int m = 0; m < 4; ++m)
            acc2[m] = __builtin_amdgcn_mfma_f32_16x16x32_bf16(A2[m], W1frag[ft], acc2[m], 0, 0, 0);
    }
#pragma unroll
    for (int m = 0; m < 4; ++m)
#pragma unroll
        for (int r = 0; r < 4; ++r) {
            float c = fmaxf(acc2[m][r] + b1j, 0.f) * w2j;
            c += __shfl_xor(c, 1); c += __shfl_xor(c, 2);
            c += __shfl_xor(c, 4); c += __shfl_xor(c, 8);
            if (l15 == 0) atomicAdd(&gsumS[m * 16 + quad * 4 + r], c);
        }
    __syncthreads();
    if (t < KNBR) {
        const float invT = 1.0f / loadSg<BF16IN>(temp, 0);
        attnS[t] *= 1.0f / (1.0f + expf(-gsumS[t] * invT));
    }
    __syncthreads();
    if (t < EMBED_D) {
        float mx = -INFINITY;
        for (int k = 0; k < KNBR; ++k)
            mx = fmaxf(mx, attnS[k] * b2f(Ns[k * NSTR + t]));
        const float o = tanhf(mx + loadSg<BF16IN>(gcnb, t));
        if constexpr (BF16IN)
            ((unsigned short*)out)[(long)b * EMBED_D + t] = f2b(o);
        else
            ((float*)out)[(long)b * EMBED_D + t] = o;
    }
}

__global__ __launch_bounds__(256, 2)
void embed_matcher_fallback(const int* entity, const int* conn, const void* emb,
                            const void* gw, const void* gwb, const void* gcnb,
                            const void* w1, const void* b1, const void* w2,
                            const void* b2, const void* temp, void* out)
{
    __shared__ __align__(16) unsigned short Xs[MROWS * XSTR];
    __shared__ __align__(16) unsigned short Ns[MROWS * NSTR];
    __shared__ float selfE[EMBED_D];
    __shared__ float scoresS[MROWS];
    __shared__ float attnS[MROWS];
    __shared__ float gsumS[MROWS];
    if (detect_bf16((const unsigned short*)emb))
        body_fb<true>(entity, conn, emb, gw, gwb, gcnb, w1, b1, w2, b2, temp, out,
                      Xs, Ns, selfE, scoresS, attnS, gsumS);
    else
        body_fb<false>(entity, conn, emb, gw, gwb, gcnb, w1, b1, w2, b2, temp, out,
                       Xs, Ns, selfE, scoresS, attnS, gsumS);
}

// ---------------- launcher ----------------

static inline size_t align256(size_t x) { return (x + 255) & ~(size_t)255; }

extern "C" void kernel_launch(void* const* d_in, const int* in_sizes, int n_in,
                              void* d_out, int out_size, void* d_ws, size_t ws_size,
                              hipStream_t stream) {
    (void)n_in; (void)out_size;
    const int B = in_sizes[0];  // 8192

    // ws layout: bf16 copies of all float tensors
    const long n_emb = in_sizes[2];
    size_t off[9], cur = 0;
    const int ns[8] = {in_sizes[3], in_sizes[4], in_sizes[5], in_sizes[6],
                       in_sizes[7], in_sizes[8], in_sizes[9], in_sizes[10]};
    off[0] = 0; cur = align256((size_t)n_emb * 2);                      // emb
    for (int i = 0; i < 8; ++i) { off[i + 1] = cur; cur = align256(cur + (size_t)ns[i] * 2); }

    if (ws_size < cur) {
        embed_matcher_fallback<<<B, 256, 0, stream>>>(
            (const int*)d_in[0], (const int*)d_in[1],
            d_in[2], d_in[3], d_in[4], d_in[5],
            d_in[6], d_in[7], d_in[8], d_in[9], d_in[10], d_out);
        return;
    }

    char* ws = (char*)d_ws;
    unsigned short* emb_b = (unsigned short*)(ws + off[0]);

    // tiny tensors: gwb, gcnb, b1, w2, b2, temp  (input idx 4,5,7,8,9,10)
    TinyTensors tt;
    const int tin[6] = {4, 5, 7, 8, 9, 10};
    for (int i = 0; i < 6; ++i) {
        tt.src[i] = d_in[tin[i]];
        tt.dst[i] = (unsigned short*)(ws + off[tin[i] - 2]);
        tt.n[i] = in_sizes[tin[i]];
    }

    const long n8 = n_emb / 8;
    const int nEmb = (int)((n8 + 255) / 256);
    const long gw8 = in_sizes[3] / 8;              // 4096 chunks
    const long w18 = in_sizes[6] / 8;              // 1024 chunks
    convert_all_kernel<<<nEmb + 20 + 1, 256, 0, stream>>>(
        d_in[2], emb_b, n8, nEmb,
        d_in[3], (unsigned short*)(ws + off[1]), gw8,
        d_in[6], (unsigned short*)(ws + off[4]), w18,
        tt);

    embed_matcher_fast<<<B, 256, 0, stream>>>(
        (const int*)d_in[0], (const int*)d_in[1],
        emb_b,
        (const unsigned short*)(ws + off[1]),   // gw
        (const unsigned short*)(ws + off[2]),   // gwb
        (const unsigned short*)(ws + off[3]),   // gcnb
        (const unsigned short*)(ws + off[4]),   // w1
        (const unsigned short*)(ws + off[5]),   // b1
        (const unsigned short*)(ws + off[6]),   // w2
        (const unsigned short*)(ws + off[7]),   // b2
        (const unsigned short*)(ws + off[8]),   // temp
        d_in[2],                                // raw emb for dtype probe
        d_out);
}

// Round 9
// 278.136 us; speedup vs baseline: 1.4339x; 1.0207x over previous
//
#include <hip/hip_runtime.h>

#define EMBED_D 128
#define KNBR 50
#define STR 136       // unified LDS row stride (128 + 8 pad; 2-way bank alias = free, m136)
#define ZROW 50       // all-zero X row for m=3 tail lanes
#define XSTR 264      // (fallback only)
#define NSTR 136      // (fallback only)
#define MROWS 64

typedef __attribute__((ext_vector_type(8))) short short8;    // 8 bf16 = 4 VGPRs (MFMA A/B frag)
typedef __attribute__((ext_vector_type(4))) float floatx4;   // MFMA C/D frag

__device__ __forceinline__ float b2f(unsigned short u) {
    union { unsigned int i; float f; } v;
    v.i = ((unsigned int)u) << 16;
    return v.f;
}
__device__ __forceinline__ unsigned short f2b(float f) {
    union { float f; unsigned int i; } v;
    v.f = f;
    return (unsigned short)((v.i + 0x7fffu + ((v.i >> 16) & 1u)) >> 16);  // RNE, finite-only
}

// bf16 emb data (N(0,0.02)) decodes to |v| < 0.15 everywhere; fp32 data has
// random low-mantissa words -> some finite |v| >= 1.0 with P ~ 1-2e-10.
__device__ __forceinline__ bool detect_bf16(const unsigned short* p) {
    float mx = 0.f;
#pragma unroll
    for (int i = 0; i < 64; ++i) {
        const float a = fabsf(b2f(p[i]));
        if (a < 3.0e38f && a > mx) mx = a;
    }
    return mx < 1.0f;
}

// ---------------- preprocessing (2 chunks/thread; straggler-free) ----------------

struct TinyTensors {
    const void* src[6];
    unsigned short* dst[6];
    int n[6];
};

__device__ __forceinline__ void conv_chunk(const void* src, unsigned short* dst,
                                           long i, bool isbf) {
    if (isbf) {
        *(short8*)(dst + i * 8) = *(const short8*)((const unsigned short*)src + i * 8);
    } else {
        const float* p = (const float*)src + i * 8;
        const floatx4 a = *(const floatx4*)p;
        const floatx4 c = *(const floatx4*)(p + 4);
        short8 r;
        r[0] = (short)f2b(a[0]); r[1] = (short)f2b(a[1]);
        r[2] = (short)f2b(a[2]); r[3] = (short)f2b(a[3]);
        r[4] = (short)f2b(c[0]); r[5] = (short)f2b(c[1]);
        r[6] = (short)f2b(c[2]); r[7] = (short)f2b(c[3]);
        *(short8*)(dst + i * 8) = r;
    }
}

__global__ void convert_all_kernel(const void* __restrict__ emb_src, unsigned short* __restrict__ emb_dst,
                                   long n8, int nEmb,
                                   const void* __restrict__ gw_src, unsigned short* __restrict__ gw_dst,
                                   long gw8,
                                   const void* __restrict__ w1_src, unsigned short* __restrict__ w1_dst,
                                   long w18,
                                   TinyTensors tt) {
    __shared__ int isbfS;
    if (threadIdx.x == 0) isbfS = detect_bf16((const unsigned short*)emb_src) ? 1 : 0;
    __syncthreads();
    const bool isbf = (isbfS != 0);
    const int bid = blockIdx.x;

    if (bid < nEmb) {   // 2 chunks (64 B src) per thread
        const long i0 = (long)bid * 512 + threadIdx.x;
        if (i0 < n8) conv_chunk(emb_src, emb_dst, i0, isbf);
        const long i1 = i0 + 256;
        if (i1 < n8) conv_chunk(emb_src, emb_dst, i1, isbf);
    } else if (bid < nEmb + 20) {
        const long q = (long)(bid - nEmb) * 256 + threadIdx.x;   // gw8+w18 = 5120 chunks
        if (q < gw8) conv_chunk(gw_src, gw_dst, q, isbf);
        else if (q < gw8 + w18) conv_chunk(w1_src, w1_dst, q - gw8, isbf);
    } else {
#pragma unroll
        for (int ti = 0; ti < 6; ++ti) {
            const int n = tt.n[ti];
            for (int i = threadIdx.x; i < n; i += 256) {
                const float v = isbf ? b2f(((const unsigned short*)tt.src[ti])[i])
                                     : ((const float*)tt.src[ti])[i];
                tt.dst[ti][i] = f2b(v);
            }
        }
    }
}

// ---------------- main kernel: K-split, 18.9 KB LDS, NATURAL <=64 VGPR ----------------
// __launch_bounds__(256,4): r7 measured this body at VGPR=60 <= 64, which the
// HW can run at 8 waves/SIMD. Forcing (256,8) made the allocator emit VGPR=32
// -> 156 MB of spill stores (r8); (256,5) similarly (r4/r5). DO NOT raise the
// second arg: let LDS (18.9 KB -> 8 blocks/CU) and natural VGPR set occupancy.

__global__ __launch_bounds__(256, 4)
void embed_matcher_fast(const int* __restrict__ entity, const int* __restrict__ conn,
                        const unsigned short* __restrict__ emb,   // bf16 staged
                        const unsigned short* __restrict__ gw,
                        const unsigned short* __restrict__ gwb,
                        const unsigned short* __restrict__ gcnb,
                        const unsigned short* __restrict__ w1,
                        const unsigned short* __restrict__ b1,
                        const unsigned short* __restrict__ w2,
                        const unsigned short* __restrict__ b2,
                        const unsigned short* __restrict__ temp,
                        const void* __restrict__ emb_raw,         // for output-dtype probe
                        void* __restrict__ out)
{
    __shared__ __align__(16) unsigned short XNs[MROWS * STR];  // 17408 B, triple-reused
    __shared__ float selfE[EMBED_D];
    __shared__ float scoresS[MROWS];
    __shared__ float attnS[MROWS];
    __shared__ float gsumS[MROWS];
    __shared__ int flagS;

    const int t = threadIdx.x;
    const int b = blockIdx.x;
    const int lane = t & 63;
    const int wave = t >> 6;
    const int l15 = lane & 15;
    const int quad = lane >> 4;
    const int cbase = b * (KNBR * 2);

    const int r3row = 48 + l15;
    const int row3 = (r3row < KNBR) ? r3row : ZROW;      // m=3 tail -> shared zero row

    floatx4 acc[4][2];
    const floatx4 fzero = {0.f, 0.f, 0.f, 0.f};
#pragma unroll
    for (int m = 0; m < 4; ++m)
#pragma unroll
        for (int nn = 0; nn < 2; ++nn) acc[m][nn] = fzero;

    // ---- P0: gather half 0 (rel) + block setup ----
    {
        int syms[4];
#pragma unroll
        for (int i = 0; i < 4; ++i) {
            const int c = t + 256 * i;                   // c = k*16 + j, 800 chunks
            syms[i] = (c < KNBR * 16) ? conn[cbase + ((c >> 4) << 1)] : 0;
        }
#pragma unroll
        for (int i = 0; i < 4; ++i) {
            const int c = t + 256 * i;
            if (c < KNBR * 16) {
                const short8 v = *(const short8*)(emb + (long)syms[i] * EMBED_D + (c & 15) * 8);
                *(short8*)(XNs + (c >> 4) * STR + (c & 15) * 8) = v;
            }
        }
        const short8 z8 = {0, 0, 0, 0, 0, 0, 0, 0};
        if (t < 17)                                      // zero row: 136 elems = 17 chunks
            *(short8*)(XNs + ZROW * STR + t * 8) = z8;
        if (t < EMBED_D) selfE[t] = b2f(emb[(long)entity[b] * EMBED_D + t]);
        if (t < MROWS) {
            gsumS[t] = b2f(b2[0]);
            scoresS[t] = 0.f;
        }
        if (t == 0) flagS = detect_bf16((const unsigned short*)emb_raw) ? 1 : 0;
    }
    __syncthreads();

    // ---- P1a: accumulate rel half (k = 0..127) ----
#pragma unroll
    for (int ft = 0; ft < 4; ++ft) {
        const int cofs = ft * 32 + quad * 8;
        short8 A[4];
#pragma unroll
        for (int m = 0; m < 3; ++m)
            A[m] = *(const short8*)(XNs + (m * 16 + l15) * STR + cofs);
        A[3] = *(const short8*)(XNs + row3 * STR + cofs);
#pragma unroll
        for (int m = 0; m < 4; ++m)
#pragma unroll
            for (int nn = 0; nn < 2; ++nn) {
                const short8 B = *(const short8*)(gw + (wave * 32 + nn * 16 + l15) * 256 + cofs);
                acc[m][nn] = __builtin_amdgcn_mfma_f32_16x16x32_bf16(A[m], B, acc[m][nn], 0, 0, 0);
            }
    }
    __syncthreads();   // all waves done reading X half 0

    // ---- P0c: gather half 1 (ent) into the same tile ----
    {
        int syms[4];
#pragma unroll
        for (int i = 0; i < 4; ++i) {
            const int c = t + 256 * i;
            syms[i] = (c < KNBR * 16) ? conn[cbase + ((c >> 4) << 1) + 1] : 0;
        }
#pragma unroll
        for (int i = 0; i < 4; ++i) {
            const int c = t + 256 * i;
            if (c < KNBR * 16) {
                const short8 v = *(const short8*)(emb + (long)syms[i] * EMBED_D + (c & 15) * 8);
                *(short8*)(XNs + (c >> 4) * STR + (c & 15) * 8) = v;
            }
        }
        // row ZROW untouched -> stays zero
    }
    __syncthreads();

    // ---- P1b: accumulate ent half (k = 128..255) ----
#pragma unroll
    for (int ft = 0; ft < 4; ++ft) {
        const int cofs = ft * 32 + quad * 8;
        short8 A[4];
#pragma unroll
        for (int m = 0; m < 3; ++m)
            A[m] = *(const short8*)(XNs + (m * 16 + l15) * STR + cofs);
        A[3] = *(const short8*)(XNs + row3 * STR + cofs);
#pragma unroll
        for (int m = 0; m < 4; ++m)
#pragma unroll
            for (int nn = 0; nn < 2; ++nn) {
                const short8 B = *(const short8*)(gw + (wave * 32 + nn * 16 + l15) * 256 + 128 + cofs);
                acc[m][nn] = __builtin_amdgcn_mfma_f32_16x16x32_bf16(A[m], B, acc[m][nn], 0, 0, 0);
            }
    }
    __syncthreads();   // X dead; reuse XNs as the nbr tile

    // ---- P1 epilogue: bias + Ns store (bf16) + scores from fp32 acc ----
    // C/D layout: row = m*16 + quad*4 + r, col = wave*32 + nn*16 + l15.
    {
        const int dcol0 = wave * 32 + l15;
        const int dcol1 = dcol0 + 16;
        const float bias0 = b2f(gwb[dcol0]);
        const float bias1 = b2f(gwb[dcol1]);
        const float se0 = selfE[dcol0];
        const float se1 = selfE[dcol1];
#pragma unroll
        for (int m = 0; m < 4; ++m)
#pragma unroll
            for (int r = 0; r < 4; ++r) {
                const int row = m * 16 + quad * 4 + r;
                const float v0 = acc[m][0][r] + bias0;
                const float v1 = acc[m][1][r] + bias1;
                XNs[row * STR + dcol0] = f2b(v0);
                XNs[row * STR + dcol1] = f2b(v1);
                float p = se0 * v0 + se1 * v1;
                p += __shfl_xor(p, 1);                   // reduce across the 16 l15 lanes
                p += __shfl_xor(p, 2);
                p += __shfl_xor(p, 4);
                p += __shfl_xor(p, 8);
                if (l15 == 0) atomicAdd(&scoresS[row], p);
            }
    }
    __syncthreads();

    // ---- softmax over k (wave 0; other waves fall through to P3) ----
    if (t < 64) {
        const float s = (t < KNBR) ? scoresS[t] * 0.088388347648318447f : -INFINITY;  // /sqrt(128)
        float mx = s;
#pragma unroll
        for (int o = 32; o > 0; o >>= 1) mx = fmaxf(mx, __shfl_xor(mx, o));
        const float e = (t < KNBR) ? expf(s - mx) : 0.f;
        float sum = e;
#pragma unroll
        for (int o = 32; o > 0; o >>= 1) sum += __shfl_xor(sum, o);
        attnS[t] = e / sum;
    }

    // ---- P3: gate MLP: h = relu(nbr.w1^T + b1); logit = h.w2 ----
    const float b1j = b2f(b1[wave * 16 + l15]);
    const float w2j = b2f(w2[wave * 16 + l15]);
    floatx4 acc2[4];
#pragma unroll
    for (int m = 0; m < 4; ++m) acc2[m] = fzero;
#pragma unroll
    for (int ft = 0; ft < 4; ++ft) {
        const short8 W1 = *(const short8*)(w1 + (wave * 16 + l15) * 128 + ft * 32 + quad * 8);
        short8 A2[4];
#pragma unroll
        for (int m = 0; m < 4; ++m)
            A2[m] = *(const short8*)(XNs + (m * 16 + l15) * STR + ft * 32 + quad * 8);
#pragma unroll
        for (int m = 0; m < 4; ++m)
            acc2[m] = __builtin_amdgcn_mfma_f32_16x16x32_bf16(A2[m], W1, acc2[m], 0, 0, 0);
    }
#pragma unroll
    for (int m = 0; m < 4; ++m)
#pragma unroll
        for (int r = 0; r < 4; ++r) {
            float c = fmaxf(acc2[m][r] + b1j, 0.f) * w2j;
            c += __shfl_xor(c, 1);
            c += __shfl_xor(c, 2);
            c += __shfl_xor(c, 4);
            c += __shfl_xor(c, 8);
            if (l15 == 0) atomicAdd(&gsumS[m * 16 + quad * 4 + r], c);
        }
    __syncthreads();

    // ---- P4a: fold gate into attn ----
    if (t < KNBR) {
        const float invT = 1.0f / b2f(temp[0]);
        const float g = 1.0f / (1.0f + expf(-gsumS[t] * invT));
        attnS[t] *= g;
    }
    __syncthreads();

    // ---- P4b: out[d] = tanh(max_k(attn*gate*nbr) + gcn_b) ----
    if (t < EMBED_D) {
        float mx = -INFINITY;
#pragma unroll
        for (int k = 0; k < KNBR; ++k)
            mx = fmaxf(mx, attnS[k] * b2f(XNs[k * STR + t]));
        const float o = tanhf(mx + b2f(gcnb[t]));
        if (flagS)
            ((unsigned short*)out)[(long)b * EMBED_D + t] = f2b(o);
        else
            ((float*)out)[(long)b * EMBED_D + t] = o;
    }
}

// ---------------- fallback (round-2 proven kernel, used only if ws too small) ----------------

template <bool BF16IN>
__device__ __forceinline__ short8 load8g(const void* base, long off) {
    if constexpr (BF16IN) {
        return *(const short8*)((const unsigned short*)base + off);
    } else {
        const float* p = (const float*)base + off;
        const floatx4 a = *(const floatx4*)p;
        const floatx4 c = *(const floatx4*)(p + 4);
        short8 r;
        r[0] = (short)f2b(a[0]); r[1] = (short)f2b(a[1]);
        r[2] = (short)f2b(a[2]); r[3] = (short)f2b(a[3]);
        r[4] = (short)f2b(c[0]); r[5] = (short)f2b(c[1]);
        r[6] = (short)f2b(c[2]); r[7] = (short)f2b(c[3]);
        return r;
    }
}
template <bool BF16IN>
__device__ __forceinline__ float loadSg(const void* base, long off) {
    if constexpr (BF16IN) return b2f(((const unsigned short*)base)[off]);
    else return ((const float*)base)[off];
}

template <bool BF16IN>
__device__ __forceinline__ void body_fb(
    const int* entity, const int* conn, const void* emb, const void* gw,
    const void* gwb, const void* gcnb, const void* w1, const void* b1,
    const void* w2, const void* b2, const void* temp, void* out,
    unsigned short* Xs, unsigned short* Ns,
    float* selfE, float* scoresS, float* attnS, float* gsumS)
{
    const int t = threadIdx.x, b = blockIdx.x;
    const int lane = t & 63, wave = t >> 6, l15 = lane & 15, quad = lane >> 4;
    short8 Bfrag[8][2];
#pragma unroll
    for (int ft = 0; ft < 8; ++ft)
#pragma unroll
        for (int nn = 0; nn < 2; ++nn)
            Bfrag[ft][nn] = load8g<BF16IN>(gw, (wave * 32 + nn * 16 + l15) * 256 + ft * 32 + quad * 8);
    short8 W1frag[4];
#pragma unroll
    for (int ft = 0; ft < 4; ++ft)
        W1frag[ft] = load8g<BF16IN>(w1, (wave * 16 + l15) * 128 + ft * 32 + quad * 8);
    const float b1j = loadSg<BF16IN>(b1, wave * 16 + l15);
    const float w2j = loadSg<BF16IN>(w2, wave * 16 + l15);
    {
        const int cbase = b * (KNBR * 2);
        for (int c = t; c < KNBR * 2 * 16; c += 256) {
            const int r = c >> 4, j = c & 15;
            const int sym = conn[cbase + r];
            *(short8*)(Xs + (r >> 1) * XSTR + (r & 1) * 128 + j * 8) =
                load8g<BF16IN>(emb, (long)sym * EMBED_D + j * 8);
        }
        for (int i = t; i < (MROWS - KNBR) * 256; i += 256)
            Xs[(KNBR + (i >> 8)) * XSTR + (i & 255)] = 0;
        if (t < EMBED_D) selfE[t] = loadSg<BF16IN>(emb, (long)entity[b] * EMBED_D + t);
        if (t < MROWS) gsumS[t] = loadSg<BF16IN>(b2, 0);
    }
    __syncthreads();
    floatx4 acc[4][2];
    const floatx4 fzero = {0.f, 0.f, 0.f, 0.f};
#pragma unroll
    for (int m = 0; m < 4; ++m)
#pragma unroll
        for (int nn = 0; nn < 2; ++nn) acc[m][nn] = fzero;
#pragma unroll
    for (int ft = 0; ft < 8; ++ft) {
        short8 A[4];
#pragma unroll
        for (int m = 0; m < 4; ++m)
            A[m] = *(const short8*)(Xs + (m * 16 + l15) * XSTR + ft * 32 + quad * 8);
#pragma unroll
        for (int m = 0; m < 4; ++m)
#pragma unroll
            for (int nn = 0; nn < 2; ++nn)
                acc[m][nn] = __builtin_amdgcn_mfma_f32_16x16x32_bf16(A[m], Bfrag[ft][nn], acc[m][nn], 0, 0, 0);
    }
#pragma unroll
    for (int nn = 0; nn < 2; ++nn) {
        const int dcol = wave * 32 + nn * 16 + l15;
        const float bias = loadSg<BF16IN>(gwb, dcol);
#pragma unroll
        for (int m = 0; m < 4; ++m)
#pragma unroll
            for (int r = 0; r < 4; ++r)
                Ns[(m * 16 + quad * 4 + r) * NSTR + dcol] = f2b(acc[m][nn][r] + bias);
    }
    __syncthreads();
    {
        const int k = t >> 2, q = t & 3;
        float p = 0.f;
        if (k < KNBR) {
            const unsigned short* nr = Ns + k * NSTR + q * 32;
            const float* se = selfE + q * 32;
#pragma unroll
            for (int i = 0; i < 32; ++i) p += se[i] * b2f(nr[i]);
        }
        p += __shfl_xor(p, 1);
        p += __shfl_xor(p, 2);
        if (k < KNBR && q == 0) scoresS[k] = p * 0.088388347648318447f;
    }
    __syncthreads();
    if (t < 64) {
        const float s = (t < KNBR) ? scoresS[t] : -INFINITY;
        float mx = s;
#pragma unroll
        for (int o = 32; o > 0; o >>= 1) mx = fmaxf(mx, __shfl_xor(mx, o));
        const float e = (t < KNBR) ? expf(s - mx) : 0.f;
        float sum = e;
#pragma unroll
        for (int o = 32; o > 0; o >>= 1) sum += __shfl_xor(sum, o);
        attnS[t] = e / sum;
    }
    floatx4 acc2[4];
#pragma unroll
    for (int m = 0; m < 4; ++m) acc2[m] = fzero;
#pragma unroll
    for (int ft = 0; ft < 4; ++ft) {
        short8 A2[4];
#pragma unroll
        for (int m = 0; m < 4; ++m)
            A2[m] = *(const short8*)(Ns + (m * 16 + l15) * NSTR + ft * 32 + quad * 8);
#pragma unroll
        for (int m = 0; m < 4; ++m)
            acc2[m] = __builtin_amdgcn_mfma_f32_16x16x32_bf16(A2[m], W1frag[ft], acc2[m], 0, 0, 0);
    }
#pragma unroll
    for (int m = 0; m < 4; ++m)
#pragma unroll
        for (int r = 0; r < 4; ++r) {
            float c = fmaxf(acc2[m][r] + b1j, 0.f) * w2j;
            c += __shfl_xor(c, 1); c += __shfl_xor(c, 2);
            c += __shfl_xor(c, 4); c += __shfl_xor(c, 8);
            if (l15 == 0) atomicAdd(&gsumS[m * 16 + quad * 4 + r], c);
        }
    __syncthreads();
    if (t < KNBR) {
        const float invT = 1.0f / loadSg<BF16IN>(temp, 0);
        attnS[t] *= 1.0f / (1.0f + expf(-gsumS[t] * invT));
    }
    __syncthreads();
    if (t < EMBED_D) {
        float mx = -INFINITY;
        for (int k = 0; k < KNBR; ++k)
            mx = fmaxf(mx, attnS[k] * b2f(Ns[k * NSTR + t]));
        const float o = tanhf(mx + loadSg<BF16IN>(gcnb, t));
        if constexpr (BF16IN)
            ((unsigned short*)out)[(long)b * EMBED_D + t] = f2b(o);
        else
            ((float*)out)[(long)b * EMBED_D + t] = o;
    }
}

__global__ __launch_bounds__(256, 2)
void embed_matcher_fallback(const int* entity, const int* conn, const void* emb,
                            const void* gw, const void* gwb, const void* gcnb,
                            const void* w1, const void* b1, const void* w2,
                            const void* b2, const void* temp, void* out)
{
    __shared__ __align__(16) unsigned short Xs[MROWS * XSTR];
    __shared__ __align__(16) unsigned short Ns[MROWS * NSTR];
    __shared__ float selfE[EMBED_D];
    __shared__ float scoresS[MROWS];
    __shared__ float attnS[MROWS];
    __shared__ float gsumS[MROWS];
    if (detect_bf16((const unsigned short*)emb))
        body_fb<true>(entity, conn, emb, gw, gwb, gcnb, w1, b1, w2, b2, temp, out,
                      Xs, Ns, selfE, scoresS, attnS, gsumS);
    else
        body_fb<false>(entity, conn, emb, gw, gwb, gcnb, w1, b1, w2, b2, temp, out,
                       Xs, Ns, selfE, scoresS, attnS, gsumS);
}

// ---------------- launcher ----------------

static inline size_t align256(size_t x) { return (x + 255) & ~(size_t)255; }

extern "C" void kernel_launch(void* const* d_in, const int* in_sizes, int n_in,
                              void* d_out, int out_size, void* d_ws, size_t ws_size,
                              hipStream_t stream) {
    (void)n_in; (void)out_size;
    const int B = in_sizes[0];  // 8192

    // ws layout: bf16 copies of all float tensors
    const long n_emb = in_sizes[2];
    size_t off[9], cur = 0;
    const int ns[8] = {in_sizes[3], in_sizes[4], in_sizes[5], in_sizes[6],
                       in_sizes[7], in_sizes[8], in_sizes[9], in_sizes[10]};
    off[0] = 0; cur = align256((size_t)n_emb * 2);                      // emb
    for (int i = 0; i < 8; ++i) { off[i + 1] = cur; cur = align256(cur + (size_t)ns[i] * 2); }

    if (ws_size < cur) {
        embed_matcher_fallback<<<B, 256, 0, stream>>>(
            (const int*)d_in[0], (const int*)d_in[1],
            d_in[2], d_in[3], d_in[4], d_in[5],
            d_in[6], d_in[7], d_in[8], d_in[9], d_in[10], d_out);
        return;
    }

    char* ws = (char*)d_ws;
    unsigned short* emb_b = (unsigned short*)(ws + off[0]);

    // tiny tensors: gwb, gcnb, b1, w2, b2, temp  (input idx 4,5,7,8,9,10)
    TinyTensors tt;
    const int tin[6] = {4, 5, 7, 8, 9, 10};
    for (int i = 0; i < 6; ++i) {
        tt.src[i] = d_in[tin[i]];
        tt.dst[i] = (unsigned short*)(ws + off[tin[i] - 2]);
        tt.n[i] = in_sizes[tin[i]];
    }

    const long n8 = n_emb / 8;
    const int nEmb = (int)((n8 + 511) / 512);      // 2 chunks/thread
    const long gw8 = in_sizes[3] / 8;              // 4096 chunks
    const long w18 = in_sizes[6] / 8;              // 1024 chunks
    convert_all_kernel<<<nEmb + 20 + 1, 256, 0, stream>>>(
        d_in[2], emb_b, n8, nEmb,
        d_in[3], (unsigned short*)(ws + off[1]), gw8,
        d_in[6], (unsigned short*)(ws + off[4]), w18,
        tt);

    embed_matcher_fast<<<B, 256, 0, stream>>>(
        (const int*)d_in[0], (const int*)d_in[1],
        emb_b,
        (const unsigned short*)(ws + off[1]),   // gw
        (const unsigned short*)(ws + off[2]),   // gwb
        (const unsigned short*)(ws + off[3]),   // gcnb
        (const unsigned short*)(ws + off[4]),   // w1
        (const unsigned short*)(ws + off[5]),   // b1
        (const unsigned short*)(ws + off[6]),   // w2
        (const unsigned short*)(ws + off[7]),   // b2
        (const unsigned short*)(ws + off[8]),   // temp
        d_in[2],                                // raw emb for dtype probe
        d_out);
}